// Round 1
// baseline (2217.284 us; speedup 1.0000x reference)
//
#include <hip/hip_runtime.h>

#define NN 16
#define CC 64
#define TT 20
#define VV 150
#define HH 8
#define DD 32
#define OO 128
#define TV 3000
#define QCH 512
#define NEL 6144000  // N*O*T*V

__device__ __forceinline__ float bf2f(unsigned short u){
  union { unsigned int i; float f; } x; x.i = ((unsigned int)u) << 16; return x.f;
}
__device__ __forceinline__ unsigned short f2bf(float f){
  union { float f; unsigned int i; } x; x.f = f;
  unsigned int r = x.i + 0x7fffu + ((x.i >> 16) & 1u);
  return (unsigned short)(r >> 16);
}
__device__ __forceinline__ float2 bfx2(unsigned int u){
  union { unsigned int i; float f; } a, b;
  a.i = u << 16; b.i = u & 0xffff0000u;
  return make_float2(a.f, b.f);
}
__device__ __forceinline__ float lrelu(float v){ return v > 0.f ? v : 0.1f*v; }

// ---------------- bias table: pe(c,v) + degree_emb[all_degree[v%25], c] ----------------
__global__ __launch_bounds__(256) void k_bias(const float* __restrict__ degree_emb,
    const int* __restrict__ all_degree, float* __restrict__ bias){
  int i = blockIdx.x*256 + threadIdx.x;
  if (i >= CC*VV) return;
  int c = i / VV, v = i % VV;
  float freq = __expf(-(float)(c >> 1) * 0.2878231366f);  // 2*ln(10000)/64
  float arg = (float)v * freq;
  float pe = (c & 1) ? cosf(arg) : sinf(arg);
  int dgi = all_degree[v % 25];
  bias[i] = pe + degree_emb[dgi*CC + c];
}

// ---------------- qkv = W_qkv @ (x + bias) + b_qkv, stored bf16 (N,512,T,V) ----------------
__global__ __launch_bounds__(256) void k_qkv(const float* __restrict__ x,
    const float* __restrict__ Wq, const float* __restrict__ bq,
    const float* __restrict__ bias, unsigned short* __restrict__ qkv){
  int lane = threadIdx.x & 63, grp = threadIdx.x >> 6;
  int gp = blockIdx.x*64 + lane;
  int n = gp / TV, pix = gp - n*TV, v = pix % VV;
  int obase = blockIdx.y*64 + grp*16;
  float acc[16];
  #pragma unroll
  for (int j=0;j<16;j++) acc[j] = bq[obase+j];
  const float* xp = x + (size_t)n*CC*TV + pix;
  const float* bp = bias + v;
  for (int c0=0;c0<CC;c0+=4){
    float s0 = xp[(size_t)(c0+0)*TV] + bp[(c0+0)*VV];
    float s1 = xp[(size_t)(c0+1)*TV] + bp[(c0+1)*VV];
    float s2 = xp[(size_t)(c0+2)*TV] + bp[(c0+2)*VV];
    float s3 = xp[(size_t)(c0+3)*TV] + bp[(c0+3)*VV];
    #pragma unroll
    for (int j=0;j<16;j++){
      const float4 w = *(const float4*)(Wq + (size_t)(obase+j)*CC + c0);
      acc[j] += s0*w.x + s1*w.y + s2*w.z + s3*w.w;
    }
  }
  unsigned short* op = qkv + (size_t)n*QCH*TV + pix;
  #pragma unroll
  for (int j=0;j<16;j++) op[(size_t)(obase+j)*TV] = f2bf(acc[j]);
}

// ---------------- att[n,h,u,v] = tanh(q·k/640)*alpha + att0 + sp_bias ----------------
__global__ __launch_bounds__(192) void k_att(const unsigned short* __restrict__ qkv,
    const float* __restrict__ alphas, const float* __restrict__ att0s,
    const float* __restrict__ sp_emb, const int* __restrict__ sp_pos,
    float* __restrict__ att){
  int v = threadIdx.x;
  int u0 = blockIdx.x*8, h = blockIdx.y, n = blockIdx.z;
  int vc = v < VV ? v : VV-1;
  const unsigned short* qb = qkv + ((size_t)n*QCH + h*DD)*TV + u0;
  const unsigned short* kb = qkv + ((size_t)n*QCH + 256 + h*DD)*TV + vc;
  float acc[8] = {0,0,0,0,0,0,0,0};
  for (int cd=0; cd<DD; cd++){
    int off = cd*TV;
    #pragma unroll 4
    for (int t=0;t<TT;t++){
      int o2 = off + t*VV;
      float kv = bf2f(kb[o2]);
      const unsigned int* q4 = (const unsigned int*)(qb + o2);
      #pragma unroll
      for (int e=0;e<4;e++){
        float2 qf = bfx2(q4[e]);
        acc[2*e]   += qf.x * kv;
        acc[2*e+1] += qf.y * kv;
      }
    }
  }
  if (v < VV){
    float al = alphas[h];
    #pragma unroll
    for (int e=0;e<8;e++){
      int u = u0 + e;
      if (u < VV){
        float a = tanhf(acc[e]*(1.f/640.f))*al
                + att0s[((size_t)h*VV+u)*VV + v]
                + sp_emb[sp_pos[u*VV+v]*HH + h];
        att[(((size_t)(n*HH+h))*VV + u)*VV + v] = a;
      }
    }
  }
}

// ---------------- y[n,h*64+c,t,v] = sum_u x[n,c,t,u]*att[n,h,u,v], stored bf16 ----------------
__global__ __launch_bounds__(192) void k_yapply(const float* __restrict__ x,
    const float* __restrict__ att, unsigned short* __restrict__ y){
  __shared__ __align__(16) float xl[64][152];
  int tid = threadIdx.x;
  int chunk = blockIdx.x, h = blockIdx.y, n = blockIdx.z;
  int r0 = chunk*64;
  for (int i=tid; i<64*152; i+=192){
    int r = i/152, uu = i - r*152;
    int row = r0 + r, c = row/20, t = row - c*20;
    xl[r][uu] = (uu < VV) ? x[((size_t)n*CC + c)*TV + t*VV + uu] : 0.f;
  }
  __syncthreads();
  int v = tid, vc = v < VV ? v : VV-1;
  const float* ap = att + ((size_t)(n*HH+h)*VV)*VV + vc;
  for (int rg=0; rg<64; rg+=16){
    float acc[16];
    #pragma unroll
    for (int j=0;j<16;j++) acc[j] = 0.f;
    for (int u0=0; u0<152; u0+=4){
      float a0 = ap[(u0+0)*VV];
      float a1 = ap[(u0+1)*VV];
      float a2 = ap[(u0+2)*VV];
      float a3 = ap[(u0+3)*VV];
      #pragma unroll
      for (int j=0;j<16;j++){
        const float4 xv = *(const float4*)&xl[rg+j][u0];
        acc[j] += xv.x*a0 + xv.y*a1 + xv.z*a2 + xv.w*a3;
      }
    }
    if (v < VV){
      #pragma unroll
      for (int j=0;j<16;j++){
        int row = r0 + rg + j, c = row/20, t = row - c*20;
        y[((size_t)n*QCH + h*CC + c)*TV + t*VV + v] = f2bf(acc[j]);
      }
    }
  }
}

// ---------------- 1x1 conv 64->128 on raw x (residual branch) ----------------
__global__ __launch_bounds__(256) void k_conv_rs(const float* __restrict__ x,
    const float* __restrict__ W, const float* __restrict__ b, float* __restrict__ out){
  int lane = threadIdx.x & 63, grp = threadIdx.x >> 6;
  int gp = blockIdx.x*64 + lane;
  int n = gp / TV, pix = gp - n*TV;
  int obase = blockIdx.y*64 + grp*16;
  float acc[16];
  #pragma unroll
  for (int j=0;j<16;j++) acc[j] = b[obase+j];
  const float* xp = x + (size_t)n*CC*TV + pix;
  for (int c0=0;c0<CC;c0+=4){
    float s0 = xp[(size_t)(c0+0)*TV];
    float s1 = xp[(size_t)(c0+1)*TV];
    float s2 = xp[(size_t)(c0+2)*TV];
    float s3 = xp[(size_t)(c0+3)*TV];
    #pragma unroll
    for (int j=0;j<16;j++){
      const float4 w = *(const float4*)(W + (size_t)(obase+j)*CC + c0);
      acc[j] += s0*w.x + s1*w.y + s2*w.z + s3*w.w;
    }
  }
  #pragma unroll
  for (int j=0;j<16;j++) out[((size_t)n*OO + obase+j)*TV + pix] = acc[j];
}

// ---------------- 1x5 conv along V, 512->128 ch, pad 2 ----------------
__global__ __launch_bounds__(256) void k_conv_out(const unsigned short* __restrict__ y,
    const float* __restrict__ W, const float* __restrict__ b, float* __restrict__ out){
  __shared__ __align__(16) float ylds[16][68];
  int tid = threadIdx.x;
  int v0 = blockIdx.x*64, t = blockIdx.y, n = blockIdx.z;
  int p0 = (tid & 7) * 8;
  int obase = (tid >> 3) * 4;
  float acc[8][4];
  #pragma unroll
  for (int pp=0;pp<8;pp++)
    #pragma unroll
    for (int oo=0;oo<4;oo++) acc[pp][oo] = 0.f;
  for (int ic0=0; ic0<QCH; ic0+=16){
    __syncthreads();
    for (int idx=tid; idx<16*68; idx+=256){
      int ic = idx/68, j = idx - ic*68;
      int vv = v0 + j - 2;
      float val = 0.f;
      if (vv >= 0 && vv < VV) val = bf2f(y[((size_t)n*QCH + ic0+ic)*TV + t*VV + vv]);
      ylds[ic][j] = val;
    }
    __syncthreads();
    for (int ic=0; ic<16; ic++){
      float w[4][5];
      const float* wp = W + (size_t)obase*2560 + (ic0+ic)*5;
      #pragma unroll
      for (int oo=0;oo<4;oo++)
        #pragma unroll
        for (int kv=0;kv<5;kv++) w[oo][kv] = wp[(size_t)oo*2560 + kv];
      const float4* yp = (const float4*)&ylds[ic][p0];
      float4 ya = yp[0], yb = yp[1], yc = yp[2];
      float yv[12] = {ya.x,ya.y,ya.z,ya.w, yb.x,yb.y,yb.z,yb.w, yc.x,yc.y,yc.z,yc.w};
      #pragma unroll
      for (int pp=0;pp<8;pp++)
        #pragma unroll
        for (int oo=0;oo<4;oo++){
          float a = acc[pp][oo];
          a += yv[pp+0]*w[oo][0] + yv[pp+1]*w[oo][1] + yv[pp+2]*w[oo][2]
             + yv[pp+3]*w[oo][3] + yv[pp+4]*w[oo][4];
          acc[pp][oo] = a;
        }
    }
  }
  #pragma unroll
  for (int pp=0;pp<8;pp++){
    int v = v0 + p0 + pp;
    if (v < VV){
      #pragma unroll
      for (int oo=0;oo<4;oo++)
        out[((size_t)n*OO + obase+oo)*TV + t*VV + v] = acc[pp][oo] + b[obase+oo];
    }
  }
}

// ---------------- 1x1 conv 128->128 ----------------
__global__ __launch_bounds__(256) void k_conv1x1(const float* __restrict__ in,
    const float* __restrict__ W, const float* __restrict__ b, float* __restrict__ out){
  int lane = threadIdx.x & 63, grp = threadIdx.x >> 6;
  int gp = blockIdx.x*64 + lane;
  int n = gp / TV, pix = gp - n*TV;
  int obase = blockIdx.y*64 + grp*16;
  float acc[16];
  #pragma unroll
  for (int j=0;j<16;j++) acc[j] = b[obase+j];
  const float* xp = in + (size_t)n*OO*TV + pix;
  for (int c0=0;c0<OO;c0+=4){
    float s0 = xp[(size_t)(c0+0)*TV];
    float s1 = xp[(size_t)(c0+1)*TV];
    float s2 = xp[(size_t)(c0+2)*TV];
    float s3 = xp[(size_t)(c0+3)*TV];
    #pragma unroll
    for (int j=0;j<16;j++){
      const float4 w = *(const float4*)(W + (size_t)(obase+j)*OO + c0);
      acc[j] += s0*w.x + s1*w.y + s2*w.z + s3*w.w;
    }
  }
  #pragma unroll
  for (int j=0;j<16;j++) out[((size_t)n*OO + obase+j)*TV + pix] = acc[j];
}

// ---------------- 3x1 conv along T, 128->128, pad 1 ----------------
__global__ __launch_bounds__(256) void k_conv_t(const float* __restrict__ in,
    const float* __restrict__ W, const float* __restrict__ b, float* __restrict__ out){
  int lane = threadIdx.x & 63, grp = threadIdx.x >> 6;
  int vt = blockIdx.x >> 1, oh = blockIdx.x & 1;
  int t = blockIdx.y, n = blockIdx.z;
  int v = vt*64 + lane;
  int vc = v < VV ? v : VV-1;
  bool vok = v < VV;
  int obase = oh*64 + grp*16;
  float acc[16];
  #pragma unroll
  for (int j=0;j<16;j++) acc[j] = b[obase+j];
  for (int g=0; g<32; g++){
    int ic = g*4;
    float xv[4][3];
    #pragma unroll
    for (int kt=0;kt<3;kt++){
      int tt = t + kt - 1;
      bool tok = (tt >= 0) && (tt < TT);
      #pragma unroll
      for (int di=0;di<4;di++)
        xv[di][kt] = tok ? in[((size_t)n*OO + ic+di)*TV + tt*VV + vc] : 0.f;
    }
    #pragma unroll
    for (int j=0;j<16;j++){
      const float4* w4 = (const float4*)(W + (size_t)(obase+j)*384 + ic*3);
      float4 w0 = w4[0], w1 = w4[1], w2 = w4[2];
      acc[j] += w0.x*xv[0][0] + w0.y*xv[0][1] + w0.z*xv[0][2] + w0.w*xv[1][0]
              + w1.x*xv[1][1] + w1.y*xv[1][2] + w1.z*xv[2][0] + w1.w*xv[2][1]
              + w2.x*xv[2][2] + w2.y*xv[3][0] + w2.z*xv[3][1] + w2.w*xv[3][2];
    }
  }
  if (vok){
    #pragma unroll
    for (int j=0;j<16;j++)
      out[((size_t)n*OO + obase+j)*TV + t*VV + v] = acc[j];
  }
}

// ---------------- per-channel mean / inv_std over (N,T,V) ----------------
__global__ __launch_bounds__(256) void k_stats(const float* __restrict__ buf, float* __restrict__ st){
  int ch = blockIdx.x, tid = threadIdx.x;
  float s = 0.f, s2 = 0.f;
  for (int n=0;n<NN;n++){
    const float* p = buf + ((size_t)n*OO + ch)*TV;
    for (int i=tid;i<TV;i+=256){ float v = p[i]; s += v; s2 += v*v; }
  }
  #pragma unroll
  for (int off=32; off; off>>=1){ s += __shfl_down(s, off); s2 += __shfl_down(s2, off); }
  __shared__ float ls[4], ls2[4];
  int w = tid >> 6;
  if ((tid & 63) == 0){ ls[w] = s; ls2[w] = s2; }
  __syncthreads();
  if (tid == 0){
    s = ls[0]+ls[1]+ls[2]+ls[3]; s2 = ls2[0]+ls2[1]+ls2[2]+ls2[3];
    float m = s * (1.f/48000.f);
    float var = s2 * (1.f/48000.f) - m*m;
    st[ch*2] = m;
    st[ch*2+1] = rsqrtf(var + 1e-5f);
  }
}

// ---------------- BN apply in-place (residual branch, no activation) ----------------
__global__ __launch_bounds__(256) void k_bn_inplace(float* __restrict__ buf,
    const float* __restrict__ st, const float* __restrict__ g, const float* __restrict__ be){
  int i = blockIdx.x*256 + threadIdx.x;
  if (i >= NEL) return;
  int ch = (i / TV) & (OO-1);
  buf[i] = (buf[i] - st[ch*2]) * st[ch*2+1] * g[ch] + be[ch];
}

// ---------------- out = lrelu(bn(c) + res), in-place on c ----------------
__global__ __launch_bounds__(256) void k_bn_add_lrelu(float* __restrict__ c,
    const float* __restrict__ st, const float* __restrict__ g, const float* __restrict__ be,
    const float* __restrict__ res){
  int i = blockIdx.x*256 + threadIdx.x;
  if (i >= NEL) return;
  int ch = (i / TV) & (OO-1);
  float v = (c[i] - st[ch*2]) * st[ch*2+1] * g[ch] + be[ch] + res[i];
  c[i] = lrelu(v);
}

// ---------------- final: lrelu(bn_t(c3) + bn_rt(c4)) ----------------
__global__ __launch_bounds__(256) void k_final(const float* __restrict__ c3,
    const float* __restrict__ st3, const float* __restrict__ g3, const float* __restrict__ be3,
    const float* __restrict__ c4, const float* __restrict__ st4, const float* __restrict__ g4,
    const float* __restrict__ be4, float* __restrict__ out){
  int i = blockIdx.x*256 + threadIdx.x;
  if (i >= NEL) return;
  int ch = (i / TV) & (OO-1);
  float a = (c3[i] - st3[ch*2]) * st3[ch*2+1] * g3[ch] + be3[ch];
  float bb = (c4[i] - st4[ch*2]) * st4[ch*2+1] * g4[ch] + be4[ch];
  out[i] = lrelu(a + bb);
}

extern "C" void kernel_launch(void* const* d_in, const int* in_sizes, int n_in,
                              void* d_out, int out_size, void* d_ws, size_t ws_size,
                              hipStream_t stream) {
  const float* x        = (const float*)d_in[0];
  const float* W_qkv    = (const float*)d_in[1];
  const float* b_qkv    = (const float*)d_in[2];
  const float* alphas   = (const float*)d_in[3];
  const float* att0s    = (const float*)d_in[4];
  const float* degree_emb = (const float*)d_in[5];
  const float* spatial_emb = (const float*)d_in[6];
  const float* W_out    = (const float*)d_in[7];
  const float* b_out    = (const float*)d_in[8];
  const float* g_out    = (const float*)d_in[9];
  const float* be_out   = (const float*)d_in[10];
  const float* W_ff     = (const float*)d_in[11];
  const float* b_ff     = (const float*)d_in[12];
  const float* g_ff     = (const float*)d_in[13];
  const float* be_ff    = (const float*)d_in[14];
  const float* W_t      = (const float*)d_in[15];
  const float* b_t      = (const float*)d_in[16];
  const float* g_t      = (const float*)d_in[17];
  const float* be_t     = (const float*)d_in[18];
  const float* W_rs     = (const float*)d_in[19];
  const float* b_rs     = (const float*)d_in[20];
  const float* g_rs     = (const float*)d_in[21];
  const float* be_rs    = (const float*)d_in[22];
  const float* W_rt     = (const float*)d_in[23];
  const float* b_rt     = (const float*)d_in[24];
  const float* g_rt     = (const float*)d_in[25];
  const float* be_rt    = (const float*)d_in[26];
  const int* all_degree = (const int*)d_in[27];
  const int* spatial_pos= (const int*)d_in[28];

  char* ws = (char*)d_ws;
  unsigned short* qkv = (unsigned short*)(ws + 0);          // 49,152,000 B; reused as y
  float* att   = (float*)(ws + 49152000);                    // 11,520,000 B
  float* bias  = (float*)(ws + 60672000);                    //     38,400 B
  float* stats = (float*)(ws + 60710400);                    //      8,192 B (5 slots x 256 f)
  float* rs    = (float*)(ws + 60718592);                    // 24,576,000 B; reused as c3
  float* c1    = (float*)(ws + 85294592);                    // 24,576,000 B; reused as c4
  float* c2    = (float*)(ws + 109870592);                   // 24,576,000 B  -> total 134.4 MB
  unsigned short* y = qkv;
  float* c3 = rs;
  float* c4 = c1;
  float* out = (float*)d_out;

  k_bias<<<dim3(38), 256, 0, stream>>>(degree_emb, all_degree, bias);
  k_qkv<<<dim3(750, 8), 256, 0, stream>>>(x, W_qkv, b_qkv, bias, qkv);
  k_att<<<dim3(19, 8, 16), 192, 0, stream>>>(qkv, alphas, att0s, spatial_emb, spatial_pos, att);
  k_yapply<<<dim3(20, 8, 16), 192, 0, stream>>>(x, att, y);

  k_conv_rs<<<dim3(750, 2), 256, 0, stream>>>(x, W_rs, b_rs, rs);
  k_stats<<<128, 256, 0, stream>>>(rs, stats + 0);
  k_bn_inplace<<<24000, 256, 0, stream>>>(rs, stats + 0, g_rs, be_rs);

  k_conv_out<<<dim3(3, 20, 16), 256, 0, stream>>>(y, W_out, b_out, c1);
  k_stats<<<128, 256, 0, stream>>>(c1, stats + 256);
  k_bn_add_lrelu<<<24000, 256, 0, stream>>>(c1, stats + 256, g_out, be_out, rs);

  k_conv1x1<<<dim3(750, 2), 256, 0, stream>>>(c1, W_ff, b_ff, c2);
  k_stats<<<128, 256, 0, stream>>>(c2, stats + 512);
  k_bn_add_lrelu<<<24000, 256, 0, stream>>>(c2, stats + 512, g_ff, be_ff, rs);

  k_conv_t<<<dim3(6, 20, 16), 256, 0, stream>>>(c2, W_t, b_t, c3);
  k_conv1x1<<<dim3(750, 2), 256, 0, stream>>>(c2, W_rt, b_rt, c4);
  k_stats<<<128, 256, 0, stream>>>(c3, stats + 768);
  k_stats<<<128, 256, 0, stream>>>(c4, stats + 1024);
  k_final<<<24000, 256, 0, stream>>>(c3, stats + 768, g_t, be_t,
                                     c4, stats + 1024, g_rt, be_rt, out);
}

// Round 2
// 1746.587 us; speedup vs baseline: 1.2695x; 1.2695x over previous
//
#include <hip/hip_runtime.h>

#define NN 16
#define CC 64
#define TT 20
#define VV 150
#define HH 8
#define DD 32
#define OO 128
#define TV 3000
#define QCH 512
#define NEL 6144000  // N*O*T*V

using bf16x8 = __attribute__((ext_vector_type(8))) short;
using f32x4  = __attribute__((ext_vector_type(4))) float;

__device__ __forceinline__ float bf2f(unsigned short u){
  union { unsigned int i; float f; } x; x.i = ((unsigned int)u) << 16; return x.f;
}
__device__ __forceinline__ unsigned short f2bf(float f){
  union { float f; unsigned int i; } x; x.f = f;
  unsigned int r = x.i + 0x7fffu + ((x.i >> 16) & 1u);
  return (unsigned short)(r >> 16);
}
__device__ __forceinline__ float2 bfx2(unsigned int u){
  union { unsigned int i; float f; } a, b;
  a.i = u << 16; b.i = u & 0xffff0000u;
  return make_float2(a.f, b.f);
}
__device__ __forceinline__ float lrelu(float v){ return v > 0.f ? v : 0.1f*v; }

// ---------------- bias table: pe(c,v) + degree_emb[all_degree[v%25], c] ----------------
__global__ __launch_bounds__(256) void k_bias(const float* __restrict__ degree_emb,
    const int* __restrict__ all_degree, float* __restrict__ bias){
  int i = blockIdx.x*256 + threadIdx.x;
  if (i >= CC*VV) return;
  int c = i / VV, v = i % VV;
  float freq = __expf(-(float)(c >> 1) * 0.2878231366f);  // 2*ln(10000)/64
  float arg = (float)v * freq;
  float pe = (c & 1) ? cosf(arg) : sinf(arg);
  int dgi = all_degree[v % 25];
  bias[i] = pe + degree_emb[dgi*CC + c];
}

// ---------------- weight pre-swizzle into A-fragment order (bf16) ----------------
// Wsw[(((ic0*5+kv)*8 + mt)*64 + lane)*8 + j] = bf16(W[o=mt*16+(lane&15)][ic=(ic0*32+(lane>>4)*8+j)][kv])
__global__ __launch_bounds__(256) void k_wprep(const float* __restrict__ W,
    unsigned short* __restrict__ Wsw){
  int g = blockIdx.x*256 + threadIdx.x;   // 40960 total
  int lane = g & 63;
  int rest = g >> 6;
  int mt = rest & 7;
  int rest2 = rest >> 3;                   // ic0*5 + kv
  int kv = rest2 % 5, ic0 = rest2 / 5;
  if (ic0 >= 16) return;
  int o = mt*16 + (lane & 15);
  int icb = ic0*32 + (lane >> 4)*8;
  unsigned short vals[8];
  #pragma unroll
  for (int j=0;j<8;j++)
    vals[j] = f2bf(W[(size_t)o*2560 + (size_t)(icb+j)*5 + kv]);
  unsigned int* dst = (unsigned int*)(Wsw + (size_t)g*8);
  #pragma unroll
  for (int j=0;j<4;j++)
    dst[j] = (unsigned int)vals[2*j] | ((unsigned int)vals[2*j+1] << 16);
}

// ---------------- qkv = W_qkv @ (x + bias) + b_qkv, stored bf16 (N,512,T,V) ----------------
__global__ __launch_bounds__(256) void k_qkv(const float* __restrict__ x,
    const float* __restrict__ Wq, const float* __restrict__ bq,
    const float* __restrict__ bias, unsigned short* __restrict__ qkv){
  int lane = threadIdx.x & 63, grp = threadIdx.x >> 6;
  int gp = blockIdx.x*64 + lane;
  int n = gp / TV, pix = gp - n*TV, v = pix % VV;
  int obase = blockIdx.y*64 + grp*16;
  float acc[16];
  #pragma unroll
  for (int j=0;j<16;j++) acc[j] = bq[obase+j];
  const float* xp = x + (size_t)n*CC*TV + pix;
  const float* bp = bias + v;
  for (int c0=0;c0<CC;c0+=4){
    float s0 = xp[(size_t)(c0+0)*TV] + bp[(c0+0)*VV];
    float s1 = xp[(size_t)(c0+1)*TV] + bp[(c0+1)*VV];
    float s2 = xp[(size_t)(c0+2)*TV] + bp[(c0+2)*VV];
    float s3 = xp[(size_t)(c0+3)*TV] + bp[(c0+3)*VV];
    #pragma unroll
    for (int j=0;j<16;j++){
      const float4 w = *(const float4*)(Wq + (size_t)(obase+j)*CC + c0);
      acc[j] += s0*w.x + s1*w.y + s2*w.z + s3*w.w;
    }
  }
  unsigned short* op = qkv + (size_t)n*QCH*TV + pix;
  #pragma unroll
  for (int j=0;j<16;j++) op[(size_t)(obase+j)*TV] = f2bf(acc[j]);
}

// ---------------- att[n,h,u,v] = tanh(q·k/640)*alpha + att0 + sp_bias ----------------
__global__ __launch_bounds__(192) void k_att(const unsigned short* __restrict__ qkv,
    const float* __restrict__ alphas, const float* __restrict__ att0s,
    const float* __restrict__ sp_emb, const int* __restrict__ sp_pos,
    float* __restrict__ att){
  int v = threadIdx.x;
  int u0 = blockIdx.x*8, h = blockIdx.y, n = blockIdx.z;
  int vc = v < VV ? v : VV-1;
  const unsigned short* qb = qkv + ((size_t)n*QCH + h*DD)*TV + u0;
  const unsigned short* kb = qkv + ((size_t)n*QCH + 256 + h*DD)*TV + vc;
  float acc[8] = {0,0,0,0,0,0,0,0};
  for (int cd=0; cd<DD; cd++){
    int off = cd*TV;
    #pragma unroll 4
    for (int t=0;t<TT;t++){
      int o2 = off + t*VV;
      float kv = bf2f(kb[o2]);
      const unsigned int* q4 = (const unsigned int*)(qb + o2);
      #pragma unroll
      for (int e=0;e<4;e++){
        float2 qf = bfx2(q4[e]);
        acc[2*e]   += qf.x * kv;
        acc[2*e+1] += qf.y * kv;
      }
    }
  }
  if (v < VV){
    float al = alphas[h];
    #pragma unroll
    for (int e=0;e<8;e++){
      int u = u0 + e;
      if (u < VV){
        float a = tanhf(acc[e]*(1.f/640.f))*al
                + att0s[((size_t)h*VV+u)*VV + v]
                + sp_emb[sp_pos[u*VV+v]*HH + h];
        att[(((size_t)(n*HH+h))*VV + u)*VV + v] = a;
      }
    }
  }
}

// ---------------- y[n,h*64+c,t,v] = sum_u x[n,c,t,u]*att[n,h,u,v], stored bf16 ----------------
__global__ __launch_bounds__(192) void k_yapply(const float* __restrict__ x,
    const float* __restrict__ att, unsigned short* __restrict__ y){
  __shared__ __align__(16) float xl[64][152];
  int tid = threadIdx.x;
  int chunk = blockIdx.x, h = blockIdx.y, n = blockIdx.z;
  int r0 = chunk*64;
  for (int i=tid; i<64*152; i+=192){
    int r = i/152, uu = i - r*152;
    int row = r0 + r, c = row/20, t = row - c*20;
    xl[r][uu] = (uu < VV) ? x[((size_t)n*CC + c)*TV + t*VV + uu] : 0.f;
  }
  __syncthreads();
  int v = tid, vc = v < VV ? v : VV-1;
  const float* ap = att + ((size_t)(n*HH+h)*VV)*VV + vc;
  for (int rg=0; rg<64; rg+=16){
    float acc[16];
    #pragma unroll
    for (int j=0;j<16;j++) acc[j] = 0.f;
    for (int u0=0; u0<152; u0+=4){
      float a0 = ap[(u0+0)*VV];
      float a1 = ap[(u0+1)*VV];
      float a2 = ap[(u0+2)*VV];
      float a3 = ap[(u0+3)*VV];
      #pragma unroll
      for (int j=0;j<16;j++){
        const float4 xv = *(const float4*)&xl[rg+j][u0];
        acc[j] += xv.x*a0 + xv.y*a1 + xv.z*a2 + xv.w*a3;
      }
    }
    if (v < VV){
      #pragma unroll
      for (int j=0;j<16;j++){
        int row = r0 + rg + j, c = row/20, t = row - c*20;
        y[((size_t)n*QCH + h*CC + c)*TV + t*VV + v] = f2bf(acc[j]);
      }
    }
  }
}

// ---------------- transpose y (N,512,T,V) -> ycl (N,T,V,512), bf16 ----------------
__global__ __launch_bounds__(256) void k_ytr(const unsigned short* __restrict__ ycf,
    unsigned short* __restrict__ ycl){
  __shared__ unsigned short tile[64*150];
  int tid = threadIdx.x;
  int t = blockIdx.x, n = blockIdx.y;
  for (int ch0=0; ch0<QCH; ch0+=64){
    __syncthreads();
    for (int i=tid; i<64*75; i+=256){
      int ch = i/75, u = i - ch*75;
      unsigned int val = *(const unsigned int*)(ycf + ((size_t)(n*QCH + ch0+ch)*TT + t)*VV + 2*u);
      *(unsigned int*)&tile[ch*150 + 2*u] = val;
    }
    __syncthreads();
    for (int i=tid; i<150*32; i+=256){
      int v = i >> 5, c2 = (i & 31)*2;
      unsigned int val = (unsigned int)tile[c2*150 + v]
                       | ((unsigned int)tile[(c2+1)*150 + v] << 16);
      *(unsigned int*)(ycl + ((size_t)(n*TT + t)*VV + v)*QCH + ch0 + c2) = val;
    }
  }
}

// ---------------- MFMA 1x5 conv along V, 512->128 ch, pad 2 ----------------
// block = (t, n); 4 waves: wave&1 -> M-half (4 m-tiles), wave>>1 -> N-half (5 n-tiles)
__global__ __launch_bounds__(256) void k_conv_out_mfma(
    const unsigned short* __restrict__ ycl,
    const unsigned short* __restrict__ Wsw,
    const float* __restrict__ bo, float* __restrict__ out){
  int tid = threadIdx.x;
  int wave = tid >> 6, lane = tid & 63;
  int l15 = lane & 15, lhi = lane >> 4;
  int t = blockIdx.x, n = blockIdx.y;
  int mtb = (wave & 1) * 4;
  int ntb = (wave >> 1) * 5;
  f32x4 acc[4][5];
  #pragma unroll
  for (int m=0;m<4;m++)
    #pragma unroll
    for (int q=0;q<5;q++) acc[m][q] = f32x4{0.f,0.f,0.f,0.f};
  const unsigned short* yb = ycl + (size_t)(n*TT + t)*VV*QCH + lhi*8;
  for (int ic0=0; ic0<16; ic0++){
    #pragma unroll
    for (int kv=0; kv<5; kv++){
      bf16x8 afr[4];
      #pragma unroll
      for (int m=0;m<4;m++)
        afr[m] = *(const bf16x8*)(Wsw + ((size_t)((ic0*5+kv)*8 + mtb + m)*64 + lane)*8);
      #pragma unroll
      for (int q=0;q<5;q++){
        int v = (ntb+q)*16 + l15 + kv - 2;
        bf16x8 bfr = {};
        if (v >= 0 && v < VV)
          bfr = *(const bf16x8*)(yb + (size_t)v*QCH + ic0*32);
        #pragma unroll
        for (int m=0;m<4;m++)
          acc[m][q] = __builtin_amdgcn_mfma_f32_16x16x32_bf16(afr[m], bfr, acc[m][q], 0, 0, 0);
      }
    }
  }
  #pragma unroll
  for (int m=0;m<4;m++){
    int o0 = (mtb+m)*16 + lhi*4;
    #pragma unroll
    for (int q=0;q<5;q++){
      int v = (ntb+q)*16 + l15;
      if (v < VV){
        #pragma unroll
        for (int r=0;r<4;r++)
          out[((size_t)(n*OO + o0 + r)*TT + t)*VV + v] = acc[m][q][r] + bo[o0+r];
      }
    }
  }
}

// ---------------- 1x1 conv 64->128 on raw x (residual branch) ----------------
__global__ __launch_bounds__(256) void k_conv_rs(const float* __restrict__ x,
    const float* __restrict__ W, const float* __restrict__ b, float* __restrict__ out){
  int lane = threadIdx.x & 63, grp = threadIdx.x >> 6;
  int gp = blockIdx.x*64 + lane;
  int n = gp / TV, pix = gp - n*TV;
  int obase = blockIdx.y*64 + grp*16;
  float acc[16];
  #pragma unroll
  for (int j=0;j<16;j++) acc[j] = b[obase+j];
  const float* xp = x + (size_t)n*CC*TV + pix;
  for (int c0=0;c0<CC;c0+=4){
    float s0 = xp[(size_t)(c0+0)*TV];
    float s1 = xp[(size_t)(c0+1)*TV];
    float s2 = xp[(size_t)(c0+2)*TV];
    float s3 = xp[(size_t)(c0+3)*TV];
    #pragma unroll
    for (int j=0;j<16;j++){
      const float4 w = *(const float4*)(W + (size_t)(obase+j)*CC + c0);
      acc[j] += s0*w.x + s1*w.y + s2*w.z + s3*w.w;
    }
  }
  #pragma unroll
  for (int j=0;j<16;j++) out[((size_t)n*OO + obase+j)*TV + pix] = acc[j];
}

// ---------------- 1x1 conv 128->128 ----------------
__global__ __launch_bounds__(256) void k_conv1x1(const float* __restrict__ in,
    const float* __restrict__ W, const float* __restrict__ b, float* __restrict__ out){
  int lane = threadIdx.x & 63, grp = threadIdx.x >> 6;
  int gp = blockIdx.x*64 + lane;
  int n = gp / TV, pix = gp - n*TV;
  int obase = blockIdx.y*64 + grp*16;
  float acc[16];
  #pragma unroll
  for (int j=0;j<16;j++) acc[j] = b[obase+j];
  const float* xp = in + (size_t)n*OO*TV + pix;
  for (int c0=0;c0<OO;c0+=4){
    float s0 = xp[(size_t)(c0+0)*TV];
    float s1 = xp[(size_t)(c0+1)*TV];
    float s2 = xp[(size_t)(c0+2)*TV];
    float s3 = xp[(size_t)(c0+3)*TV];
    #pragma unroll
    for (int j=0;j<16;j++){
      const float4 w = *(const float4*)(W + (size_t)(obase+j)*OO + c0);
      acc[j] += s0*w.x + s1*w.y + s2*w.z + s3*w.w;
    }
  }
  #pragma unroll
  for (int j=0;j<16;j++) out[((size_t)n*OO + obase+j)*TV + pix] = acc[j];
}

// ---------------- 3x1 conv along T, 128->128, pad 1 ----------------
__global__ __launch_bounds__(256) void k_conv_t(const float* __restrict__ in,
    const float* __restrict__ W, const float* __restrict__ b, float* __restrict__ out){
  int lane = threadIdx.x & 63, grp = threadIdx.x >> 6;
  int vt = blockIdx.x >> 1, oh = blockIdx.x & 1;
  int t = blockIdx.y, n = blockIdx.z;
  int v = vt*64 + lane;
  int vc = v < VV ? v : VV-1;
  bool vok = v < VV;
  int obase = oh*64 + grp*16;
  float acc[16];
  #pragma unroll
  for (int j=0;j<16;j++) acc[j] = b[obase+j];
  for (int g=0; g<32; g++){
    int ic = g*4;
    float xv[4][3];
    #pragma unroll
    for (int kt=0;kt<3;kt++){
      int tt = t + kt - 1;
      bool tok = (tt >= 0) && (tt < TT);
      #pragma unroll
      for (int di=0;di<4;di++)
        xv[di][kt] = tok ? in[((size_t)n*OO + ic+di)*TV + tt*VV + vc] : 0.f;
    }
    #pragma unroll
    for (int j=0;j<16;j++){
      const float4* w4 = (const float4*)(W + (size_t)(obase+j)*384 + ic*3);
      float4 w0 = w4[0], w1 = w4[1], w2 = w4[2];
      acc[j] += w0.x*xv[0][0] + w0.y*xv[0][1] + w0.z*xv[0][2] + w0.w*xv[1][0]
              + w1.x*xv[1][1] + w1.y*xv[1][2] + w1.z*xv[2][0] + w1.w*xv[2][1]
              + w2.x*xv[2][2] + w2.y*xv[3][0] + w2.z*xv[3][1] + w2.w*xv[3][2];
    }
  }
  if (vok){
    #pragma unroll
    for (int j=0;j<16;j++)
      out[((size_t)n*OO + obase+j)*TV + t*VV + v] = acc[j];
  }
}

// ---------------- per-channel mean / inv_std over (N,T,V) ----------------
__global__ __launch_bounds__(256) void k_stats(const float* __restrict__ buf, float* __restrict__ st){
  int ch = blockIdx.x, tid = threadIdx.x;
  float s = 0.f, s2 = 0.f;
  for (int n=0;n<NN;n++){
    const float* p = buf + ((size_t)n*OO + ch)*TV;
    for (int i=tid;i<TV;i+=256){ float v = p[i]; s += v; s2 += v*v; }
  }
  #pragma unroll
  for (int off=32; off; off>>=1){ s += __shfl_down(s, off); s2 += __shfl_down(s2, off); }
  __shared__ float ls[4], ls2[4];
  int w = tid >> 6;
  if ((tid & 63) == 0){ ls[w] = s; ls2[w] = s2; }
  __syncthreads();
  if (tid == 0){
    s = ls[0]+ls[1]+ls[2]+ls[3]; s2 = ls2[0]+ls2[1]+ls2[2]+ls2[3];
    float m = s * (1.f/48000.f);
    float var = s2 * (1.f/48000.f) - m*m;
    st[ch*2] = m;
    st[ch*2+1] = rsqrtf(var + 1e-5f);
  }
}

// ---------------- BN apply in-place (residual branch, no activation) ----------------
__global__ __launch_bounds__(256) void k_bn_inplace(float* __restrict__ buf,
    const float* __restrict__ st, const float* __restrict__ g, const float* __restrict__ be){
  int i = blockIdx.x*256 + threadIdx.x;
  if (i >= NEL) return;
  int ch = (i / TV) & (OO-1);
  buf[i] = (buf[i] - st[ch*2]) * st[ch*2+1] * g[ch] + be[ch];
}

// ---------------- out = lrelu(bn(c) + res), in-place on c ----------------
__global__ __launch_bounds__(256) void k_bn_add_lrelu(float* __restrict__ c,
    const float* __restrict__ st, const float* __restrict__ g, const float* __restrict__ be,
    const float* __restrict__ res){
  int i = blockIdx.x*256 + threadIdx.x;
  if (i >= NEL) return;
  int ch = (i / TV) & (OO-1);
  float v = (c[i] - st[ch*2]) * st[ch*2+1] * g[ch] + be[ch] + res[i];
  c[i] = lrelu(v);
}

// ---------------- final: lrelu(bn_t(c3) + bn_rt(c4)) ----------------
__global__ __launch_bounds__(256) void k_final(const float* __restrict__ c3,
    const float* __restrict__ st3, const float* __restrict__ g3, const float* __restrict__ be3,
    const float* __restrict__ c4, const float* __restrict__ st4, const float* __restrict__ g4,
    const float* __restrict__ be4, float* __restrict__ out){
  int i = blockIdx.x*256 + threadIdx.x;
  if (i >= NEL) return;
  int ch = (i / TV) & (OO-1);
  float a = (c3[i] - st3[ch*2]) * st3[ch*2+1] * g3[ch] + be3[ch];
  float bb = (c4[i] - st4[ch*2]) * st4[ch*2+1] * g4[ch] + be4[ch];
  out[i] = lrelu(a + bb);
}

extern "C" void kernel_launch(void* const* d_in, const int* in_sizes, int n_in,
                              void* d_out, int out_size, void* d_ws, size_t ws_size,
                              hipStream_t stream) {
  const float* x        = (const float*)d_in[0];
  const float* W_qkv    = (const float*)d_in[1];
  const float* b_qkv    = (const float*)d_in[2];
  const float* alphas   = (const float*)d_in[3];
  const float* att0s    = (const float*)d_in[4];
  const float* degree_emb = (const float*)d_in[5];
  const float* spatial_emb = (const float*)d_in[6];
  const float* W_out    = (const float*)d_in[7];
  const float* b_out    = (const float*)d_in[8];
  const float* g_out    = (const float*)d_in[9];
  const float* be_out   = (const float*)d_in[10];
  const float* W_ff     = (const float*)d_in[11];
  const float* b_ff     = (const float*)d_in[12];
  const float* g_ff     = (const float*)d_in[13];
  const float* be_ff    = (const float*)d_in[14];
  const float* W_t      = (const float*)d_in[15];
  const float* b_t      = (const float*)d_in[16];
  const float* g_t      = (const float*)d_in[17];
  const float* be_t     = (const float*)d_in[18];
  const float* W_rs     = (const float*)d_in[19];
  const float* b_rs     = (const float*)d_in[20];
  const float* g_rs     = (const float*)d_in[21];
  const float* be_rs    = (const float*)d_in[22];
  const float* W_rt     = (const float*)d_in[23];
  const float* b_rt     = (const float*)d_in[24];
  const float* g_rt     = (const float*)d_in[25];
  const float* be_rt    = (const float*)d_in[26];
  const int* all_degree = (const int*)d_in[27];
  const int* spatial_pos= (const int*)d_in[28];

  char* ws = (char*)d_ws;
  // region A @0 (49,152,000 B): qkv -> y_cf -> {c1 @0, c2 @24,576,000}
  // region B @49,152,000 (49,152,000 B): att -> ycl -> {c3 @49,152,000, c4 @73,728,000}
  // region E @98,304,000 (24,576,000 B): rs
  // small @122,880,000: bias (38,400) ; @122,918,400: stats (8,192) ; @122,926,592: Wsw (655,360)
  unsigned short* qkv = (unsigned short*)(ws + 0);
  unsigned short* y   = qkv;                               // y_cf reuses qkv region
  float* att   = (float*)(ws + 49152000);
  unsigned short* ycl = (unsigned short*)(ws + 49152000);  // overwrites att (dead)
  float* rs    = (float*)(ws + 98304000);
  float* bias  = (float*)(ws + 122880000);
  float* stats = (float*)(ws + 122918400);
  unsigned short* Wsw = (unsigned short*)(ws + 122926592);
  float* c1 = (float*)(ws + 0);                            // y_cf dead after k_ytr
  float* c2 = (float*)(ws + 24576000);
  float* c3 = (float*)(ws + 49152000);                     // ycl dead after conv_out
  float* c4 = (float*)(ws + 73728000);
  float* out = (float*)d_out;

  k_bias<<<dim3(38), 256, 0, stream>>>(degree_emb, all_degree, bias);
  k_wprep<<<dim3(160), 256, 0, stream>>>(W_out, Wsw);
  k_qkv<<<dim3(750, 8), 256, 0, stream>>>(x, W_qkv, b_qkv, bias, qkv);
  k_att<<<dim3(19, 8, 16), 192, 0, stream>>>(qkv, alphas, att0s, spatial_emb, spatial_pos, att);
  k_yapply<<<dim3(20, 8, 16), 192, 0, stream>>>(x, att, y);
  k_ytr<<<dim3(20, 16), 256, 0, stream>>>(y, ycl);

  k_conv_rs<<<dim3(750, 2), 256, 0, stream>>>(x, W_rs, b_rs, rs);
  k_stats<<<128, 256, 0, stream>>>(rs, stats + 0);
  k_bn_inplace<<<24000, 256, 0, stream>>>(rs, stats + 0, g_rs, be_rs);

  k_conv_out_mfma<<<dim3(20, 16), 256, 0, stream>>>(ycl, Wsw, b_out, c1);
  k_stats<<<128, 256, 0, stream>>>(c1, stats + 256);
  k_bn_add_lrelu<<<24000, 256, 0, stream>>>(c1, stats + 256, g_out, be_out, rs);

  k_conv1x1<<<dim3(750, 2), 256, 0, stream>>>(c1, W_ff, b_ff, c2);
  k_stats<<<128, 256, 0, stream>>>(c2, stats + 512);
  k_bn_add_lrelu<<<24000, 256, 0, stream>>>(c2, stats + 512, g_ff, be_ff, rs);

  k_conv_t<<<dim3(6, 20, 16), 256, 0, stream>>>(c2, W_t, b_t, c3);
  k_conv1x1<<<dim3(750, 2), 256, 0, stream>>>(c2, W_rt, b_rt, c4);
  k_stats<<<128, 256, 0, stream>>>(c3, stats + 768);
  k_stats<<<128, 256, 0, stream>>>(c4, stats + 1024);
  k_final<<<24000, 256, 0, stream>>>(c3, stats + 768, g_t, be_t,
                                     c4, stats + 1024, g_rt, be_rt, out);
}

// Round 3
// 579.840 us; speedup vs baseline: 3.8240x; 3.0122x over previous
//
#include <hip/hip_runtime.h>

#define NN 16
#define CC 64
#define TT 20
#define VV 150
#define HH 8
#define DD 32
#define OO 128
#define TV 3000
#define QCH 512
#define NPIX 48000
#define NEL 6144000  // N*O*T*V

using bf16x8 = __attribute__((ext_vector_type(8))) short;
using f32x4  = __attribute__((ext_vector_type(4))) float;

__device__ __forceinline__ float bf2f(unsigned short u){
  union { unsigned int i; float f; } x; x.i = ((unsigned int)u) << 16; return x.f;
}
__device__ __forceinline__ unsigned short f2bf(float f){
  union { float f; unsigned int i; } x; x.f = f;
  unsigned int r = x.i + 0x7fffu + ((x.i >> 16) & 1u);
  return (unsigned short)(r >> 16);
}
__device__ __forceinline__ float lrelu(float v){ return v > 0.f ? v : 0.1f*v; }

// ---------------- bias table: pe(c,v) + degree_emb[all_degree[v%25], c] ----------------
__global__ __launch_bounds__(256) void k_bias(const float* __restrict__ degree_emb,
    const int* __restrict__ all_degree, float* __restrict__ bias){
  int i = blockIdx.x*256 + threadIdx.x;
  if (i >= CC*VV) return;
  int c = i / VV, v = i % VV;
  float freq = __expf(-(float)(c >> 1) * 0.2878231366f);
  float arg = (float)v * freq;
  float pe = (c & 1) ? cosf(arg) : sinf(arg);
  int dgi = all_degree[v % 25];
  bias[i] = pe + degree_emb[dgi*CC + c];
}

// ---------------- generic A-fragment swizzler ----------------
// out[((kk*MT+mt)*64+lane)*8+j] = bf16(W[(mt*16+(lane&15))*rs + (kk*32+(lane>>4)*8+j)*ks + koff])
__global__ __launch_bounds__(256) void k_wprep_gen(const float* __restrict__ W,
    unsigned short* __restrict__ out, int MT, int KT, int rs, int ks, int koff){
  int g = blockIdx.x*256 + threadIdx.x;
  if (g >= MT*KT*64) return;
  int lane = g & 63;
  int f = g >> 6;
  int mt = f % MT, kk = f / MT;
  int row = mt*16 + (lane & 15);
  int kb = kk*32 + (lane >> 4)*8;
  unsigned int pk[4];
  #pragma unroll
  for (int j=0;j<4;j++){
    unsigned short a = f2bf(W[row*rs + (kb+2*j)*ks + koff]);
    unsigned short b = f2bf(W[row*rs + (kb+2*j+1)*ks + koff]);
    pk[j] = (unsigned int)a | ((unsigned int)b << 16);
  }
  unsigned int* dst = (unsigned int*)(out + (size_t)g*8);
  #pragma unroll
  for (int j=0;j<4;j++) dst[j] = pk[j];
}

// ---------------- x prep: xbf (N,C,T,160) bf16 zero-padded; xcl biased cl; xclr raw cl ----------------
__global__ __launch_bounds__(256) void k_xprep(const float* __restrict__ x,
    const float* __restrict__ bias, unsigned short* __restrict__ xbf,
    unsigned short* __restrict__ xcl, unsigned short* __restrict__ xclr){
  __shared__ float xl[64][153];
  int tid = threadIdx.x;
  int t = blockIdx.x, n = blockIdx.y;
  for (int idx=tid; idx<64*160; idx+=256){
    int c = idx/160, v = idx - c*160;
    float xv = 0.f;
    if (v < VV){
      xv = x[((size_t)(n*CC+c)*TT + t)*VV + v];
      xl[c][v] = xv;
    }
    xbf[((size_t)(n*CC+c)*TT + t)*160 + v] = f2bf(xv);
  }
  __syncthreads();
  size_t pixb = (size_t)(n*TT + t)*VV;
  for (int idx=tid; idx<4800; idx+=256){
    int v = idx >> 5, c2 = (idx & 31)*2;
    float a0 = xl[c2][v],   a1 = xl[c2+1][v];
    unsigned int raw = (unsigned int)f2bf(a0) | ((unsigned int)f2bf(a1) << 16);
    float b0 = a0 + bias[c2*VV + v], b1 = a1 + bias[(c2+1)*VV + v];
    unsigned int bi = (unsigned int)f2bf(b0) | ((unsigned int)f2bf(b1) << 16);
    *(unsigned int*)(xclr + (pixb + v)*CC + c2) = raw;
    *(unsigned int*)(xcl  + (pixb + v)*CC + c2) = bi;
  }
}

// ---------------- qkv MFMA: M=512, K=64, pixels; out channel-last bf16 ----------------
__global__ __launch_bounds__(256) void k_qkv_mfma(const unsigned short* __restrict__ xcl,
    const unsigned short* __restrict__ Wsw, const float* __restrict__ bq,
    unsigned short* __restrict__ qkv){
  int tid = threadIdx.x, wave = tid >> 6, lane = tid & 63;
  int l15 = lane & 15, lhi = lane >> 4;
  int pix0 = blockIdx.x*32;
  f32x4 acc[8][2];
  #pragma unroll
  for (int m=0;m<8;m++){ acc[m][0] = f32x4{0,0,0,0}; acc[m][1] = f32x4{0,0,0,0}; }
  #pragma unroll
  for (int kk=0;kk<2;kk++){
    bf16x8 bfr[2];
    #pragma unroll
    for (int q=0;q<2;q++)
      bfr[q] = *(const bf16x8*)(xcl + (size_t)(pix0 + q*16 + l15)*CC + kk*32 + lhi*8);
    #pragma unroll
    for (int m=0;m<8;m++){
      bf16x8 afr = *(const bf16x8*)(Wsw + ((size_t)(kk*32 + wave*8 + m)*64 + lane)*8);
      acc[m][0] = __builtin_amdgcn_mfma_f32_16x16x32_bf16(afr, bfr[0], acc[m][0], 0,0,0);
      acc[m][1] = __builtin_amdgcn_mfma_f32_16x16x32_bf16(afr, bfr[1], acc[m][1], 0,0,0);
    }
  }
  #pragma unroll
  for (int m=0;m<8;m++){
    int o0 = (wave*8 + m)*16 + lhi*4;
    float b0 = bq[o0], b1 = bq[o0+1], b2 = bq[o0+2], b3 = bq[o0+3];
    #pragma unroll
    for (int q=0;q<2;q++){
      int pix = pix0 + q*16 + l15;
      uint2 pk;
      pk.x = (unsigned int)f2bf(acc[m][q][0]+b0) | ((unsigned int)f2bf(acc[m][q][1]+b1) << 16);
      pk.y = (unsigned int)f2bf(acc[m][q][2]+b2) | ((unsigned int)f2bf(acc[m][q][3]+b3) << 16);
      *(uint2*)(qkv + (size_t)pix*QCH + o0) = pk;
    }
  }
}

// ---------------- att MFMA: per (h,n): G[u,v]=sum_{t,d} Q K; epilogue -> attT bf16 [n,h,160v,160u] ----------------
__global__ __launch_bounds__(256) void k_att_mfma(const unsigned short* __restrict__ qkv,
    const float* __restrict__ alphas, const float* __restrict__ att0s,
    const float* __restrict__ sp_emb, const int* __restrict__ sp_pos,
    unsigned short* __restrict__ attT){
  int tid = threadIdx.x, wave = tid >> 6, lane = tid & 63;
  int l15 = lane & 15, lhi = lane >> 4;
  int h = blockIdx.x, n = blockIdx.y;
  int utb = (wave & 1)*5, vtb = (wave >> 1)*5;
  f32x4 acc[5][5];
  #pragma unroll
  for (int ui=0;ui<5;ui++)
    #pragma unroll
    for (int vi=0;vi<5;vi++) acc[ui][vi] = f32x4{0,0,0,0};
  for (int t=0;t<TT;t++){
    size_t rowb = (size_t)(n*TT + t)*VV;
    bf16x8 afr[5], bfr[5];
    #pragma unroll
    for (int ui=0;ui<5;ui++){
      int u = (utb+ui)*16 + l15;
      afr[ui] = bf16x8{};
      if (u < VV) afr[ui] = *(const bf16x8*)(qkv + (rowb + u)*QCH + h*DD + lhi*8);
    }
    #pragma unroll
    for (int vi=0;vi<5;vi++){
      int v = (vtb+vi)*16 + l15;
      bfr[vi] = bf16x8{};
      if (v < VV) bfr[vi] = *(const bf16x8*)(qkv + (rowb + v)*QCH + 256 + h*DD + lhi*8);
    }
    #pragma unroll
    for (int ui=0;ui<5;ui++)
      #pragma unroll
      for (int vi=0;vi<5;vi++)
        acc[ui][vi] = __builtin_amdgcn_mfma_f32_16x16x32_bf16(afr[ui], bfr[vi], acc[ui][vi], 0,0,0);
  }
  float al = alphas[h];
  #pragma unroll
  for (int ui=0;ui<5;ui++){
    int u0 = (utb+ui)*16 + lhi*4;
    #pragma unroll
    for (int vi=0;vi<5;vi++){
      int v = (vtb+vi)*16 + l15;
      unsigned short hv[4];
      #pragma unroll
      for (int r=0;r<4;r++){
        int u = u0 + r;
        unsigned short val = 0;
        if (u < VV && v < VV){
          float gv = tanhf(acc[ui][vi][r]*(1.f/640.f))*al
                   + att0s[((size_t)h*VV + u)*VV + v]
                   + sp_emb[sp_pos[u*VV + v]*HH + h];
          val = f2bf(gv);
        }
        hv[r] = val;
      }
      uint2 pk;
      pk.x = (unsigned int)hv[0] | ((unsigned int)hv[1] << 16);
      pk.y = (unsigned int)hv[2] | ((unsigned int)hv[3] << 16);
      *(uint2*)(attT + ((size_t)((n*HH+h)*160) + v)*160 + u0) = pk;
    }
  }
}

// ---------------- yapply MFMA: per (n,t,h): C[v,c] = sum_u attT[v,u]*xbf[c,t,u]; out ycl bf16 ----------------
__global__ __launch_bounds__(256) void k_yapply_mfma(const unsigned short* __restrict__ attT,
    const unsigned short* __restrict__ xbf, unsigned short* __restrict__ ycl){
  int tid = threadIdx.x, wave = tid >> 6, lane = tid & 63;
  int l15 = lane & 15, lhi = lane >> 4;
  int t = blockIdx.x, n = blockIdx.y;
  int vtb = (wave & 1)*5, ctb = (wave >> 1)*2;
  for (int h=0; h<HH; h++){
    f32x4 acc[5][2];
    #pragma unroll
    for (int vi=0;vi<5;vi++){ acc[vi][0] = f32x4{0,0,0,0}; acc[vi][1] = f32x4{0,0,0,0}; }
    #pragma unroll
    for (int kk=0;kk<5;kk++){
      bf16x8 afr[5], bfr[2];
      #pragma unroll
      for (int vi=0;vi<5;vi++){
        int v = (vtb+vi)*16 + l15;
        afr[vi] = *(const bf16x8*)(attT + ((size_t)((n*HH+h)*160) + v)*160 + kk*32 + lhi*8);
      }
      #pragma unroll
      for (int ci=0;ci<2;ci++){
        int c = (ctb+ci)*16 + l15;
        bfr[ci] = *(const bf16x8*)(xbf + ((size_t)(n*CC+c)*TT + t)*160 + kk*32 + lhi*8);
      }
      #pragma unroll
      for (int vi=0;vi<5;vi++)
        #pragma unroll
        for (int ci=0;ci<2;ci++)
          acc[vi][ci] = __builtin_amdgcn_mfma_f32_16x16x32_bf16(afr[vi], bfr[ci], acc[vi][ci], 0,0,0);
    }
    size_t pixb = (size_t)(n*TT + t)*VV;
    #pragma unroll
    for (int vi=0;vi<5;vi++){
      int v0 = (vtb+vi)*16 + lhi*4;
      #pragma unroll
      for (int ci=0;ci<2;ci++){
        int c = (ctb+ci)*16 + l15;
        #pragma unroll
        for (int r=0;r<4;r++){
          int v = v0 + r;
          if (v < VV)
            ycl[(pixb + v)*QCH + h*CC + c] = f2bf(acc[vi][ci][r]);
        }
      }
    }
  }
}

// ---------------- conv_out MFMA: 1x5 along V, 512->128, channel-last in/out ----------------
__global__ __launch_bounds__(256) void k_conv_out_mfma(const unsigned short* __restrict__ ycl,
    const unsigned short* __restrict__ Wsw, float* __restrict__ out){
  int tid = threadIdx.x, wave = tid >> 6, lane = tid & 63;
  int l15 = lane & 15, lhi = lane >> 4;
  int t = blockIdx.x, n = blockIdx.y;
  int mtb = (wave & 1)*4, ntb = (wave >> 1)*5;
  f32x4 acc[4][5];
  #pragma unroll
  for (int m=0;m<4;m++)
    #pragma unroll
    for (int q=0;q<5;q++) acc[m][q] = f32x4{0,0,0,0};
  const unsigned short* yb = ycl + (size_t)(n*TT + t)*VV*QCH + lhi*8;
  for (int kk=0; kk<16; kk++){
    #pragma unroll
    for (int kv=0; kv<5; kv++){
      bf16x8 afr[4];
      #pragma unroll
      for (int m=0;m<4;m++)
        afr[m] = *(const bf16x8*)(Wsw + (size_t)kv*65536 + ((size_t)(kk*8 + mtb + m)*64 + lane)*8);
      #pragma unroll
      for (int q=0;q<5;q++){
        int v = (ntb+q)*16 + l15 + kv - 2;
        bf16x8 bfr = bf16x8{};
        if (v >= 0 && v < VV)
          bfr = *(const bf16x8*)(yb + (size_t)v*QCH + kk*32);
        #pragma unroll
        for (int m=0;m<4;m++)
          acc[m][q] = __builtin_amdgcn_mfma_f32_16x16x32_bf16(afr[m], bfr, acc[m][q], 0,0,0);
      }
    }
  }
  #pragma unroll
  for (int q=0;q<5;q++){
    int v = (ntb+q)*16 + l15;
    if (v < VV){
      #pragma unroll
      for (int m=0;m<4;m++){
        int o0 = (mtb+m)*16 + lhi*4;
        float4 val = make_float4(acc[m][q][0], acc[m][q][1], acc[m][q][2], acc[m][q][3]);
        *(float4*)(out + ((size_t)(n*TT+t)*VV + v)*OO + o0) = val;
      }
    }
  }
}

// ---------------- generic 1x1 conv MFMA: KT k-tiles, 128 out-ch, channel-last ----------------
__global__ __launch_bounds__(256) void k_conv1x1_mfma(const unsigned short* __restrict__ in,
    const unsigned short* __restrict__ Wsw, float* __restrict__ out, int KT){
  int tid = threadIdx.x, wave = tid >> 6, lane = tid & 63;
  int l15 = lane & 15, lhi = lane >> 4;
  int pix0 = blockIdx.x*64;
  int mtb = (wave & 1)*4, nqb = (wave >> 1)*2;
  int KD = KT*32;
  f32x4 acc[4][2];
  #pragma unroll
  for (int m=0;m<4;m++){ acc[m][0] = f32x4{0,0,0,0}; acc[m][1] = f32x4{0,0,0,0}; }
  for (int kk=0; kk<KT; kk++){
    bf16x8 bfr[2];
    #pragma unroll
    for (int q=0;q<2;q++)
      bfr[q] = *(const bf16x8*)(in + (size_t)(pix0 + (nqb+q)*16 + l15)*KD + kk*32 + lhi*8);
    #pragma unroll
    for (int m=0;m<4;m++){
      bf16x8 afr = *(const bf16x8*)(Wsw + ((size_t)(kk*8 + mtb + m)*64 + lane)*8);
      acc[m][0] = __builtin_amdgcn_mfma_f32_16x16x32_bf16(afr, bfr[0], acc[m][0], 0,0,0);
      acc[m][1] = __builtin_amdgcn_mfma_f32_16x16x32_bf16(afr, bfr[1], acc[m][1], 0,0,0);
    }
  }
  #pragma unroll
  for (int m=0;m<4;m++){
    int o0 = (mtb+m)*16 + lhi*4;
    #pragma unroll
    for (int q=0;q<2;q++){
      int pix = pix0 + (nqb+q)*16 + l15;
      float4 val = make_float4(acc[m][q][0], acc[m][q][1], acc[m][q][2], acc[m][q][3]);
      *(float4*)(out + (size_t)pix*OO + o0) = val;
    }
  }
}

// ---------------- conv_t MFMA: 3x1 along T, 128->128, channel-last ----------------
__global__ __launch_bounds__(256) void k_conv_t_mfma(const unsigned short* __restrict__ in,
    const unsigned short* __restrict__ Wsw, float* __restrict__ out){
  int tid = threadIdx.x, wave = tid >> 6, lane = tid & 63;
  int l15 = lane & 15, lhi = lane >> 4;
  int t = blockIdx.x, n = blockIdx.y;
  int mtb = (wave & 1)*4, ntb = (wave >> 1)*5;
  f32x4 acc[4][5];
  #pragma unroll
  for (int m=0;m<4;m++)
    #pragma unroll
    for (int q=0;q<5;q++) acc[m][q] = f32x4{0,0,0,0};
  #pragma unroll
  for (int kt=0; kt<3; kt++){
    int tt = t + kt - 1;
    if (tt < 0 || tt >= TT) continue;
    const unsigned short* ib = in + (size_t)(n*TT + tt)*VV*OO + lhi*8;
    #pragma unroll
    for (int kk=0; kk<4; kk++){
      bf16x8 afr[4];
      #pragma unroll
      for (int m=0;m<4;m++)
        afr[m] = *(const bf16x8*)(Wsw + (size_t)kt*16384 + ((size_t)(kk*8 + mtb + m)*64 + lane)*8);
      #pragma unroll
      for (int q=0;q<5;q++){
        int v = (ntb+q)*16 + l15;
        bf16x8 bfr = bf16x8{};
        if (v < VV)
          bfr = *(const bf16x8*)(ib + (size_t)v*OO + kk*32);
        #pragma unroll
        for (int m=0;m<4;m++)
          acc[m][q] = __builtin_amdgcn_mfma_f32_16x16x32_bf16(afr[m], bfr, acc[m][q], 0,0,0);
      }
    }
  }
  #pragma unroll
  for (int q=0;q<5;q++){
    int v = (ntb+q)*16 + l15;
    if (v < VV){
      #pragma unroll
      for (int m=0;m<4;m++){
        int o0 = (mtb+m)*16 + lhi*4;
        float4 val = make_float4(acc[m][q][0], acc[m][q][1], acc[m][q][2], acc[m][q][3]);
        *(float4*)(out + ((size_t)(n*TT+t)*VV + v)*OO + o0) = val;
      }
    }
  }
}

// ---------------- stats stage 1: per-block partial sums (channel-last input) ----------------
__global__ __launch_bounds__(256) void k_stats1(const float* __restrict__ in, float* __restrict__ psum){
  int tid = threadIdx.x, blk = blockIdx.x;
  int ch = tid & 127, half = tid >> 7;
  float s = 0.f, s2 = 0.f;
  for (int i=0;i<192;i++){
    int p = blk*384 + i*2 + half;
    float v = in[(size_t)p*OO + ch];
    s += v; s2 += v*v;
  }
  int idx = (blk*2 + half)*OO + ch;
  psum[idx] = s;
  psum[32000 + idx] = s2;
}

// ---------------- stats stage 2: reduce partials -> mean, invstd ----------------
__global__ __launch_bounds__(128) void k_stats2(const float* __restrict__ psum, float* __restrict__ st){
  int ch = threadIdx.x;
  float s = 0.f, s2 = 0.f;
  for (int i=0;i<250;i++){
    s  += psum[i*OO + ch];
    s2 += psum[32000 + i*OO + ch];
  }
  float m = s * (1.f/48000.f);
  float var = s2 * (1.f/48000.f) - m*m;
  st[ch*2] = m;
  st[ch*2+1] = rsqrtf(var + 1e-5f);
}

// ---------------- BN in-place fp32 channel-last (residual branch) ----------------
__global__ __launch_bounds__(256) void k_bn_rs(float* __restrict__ buf,
    const float* __restrict__ st, const float* __restrict__ g, const float* __restrict__ be){
  int i = blockIdx.x*256 + threadIdx.x;
  if (i >= NEL) return;
  int ch = i & 127;
  buf[i] = (buf[i] - st[ch*2]) * st[ch*2+1] * g[ch] + be[ch];
}

// ---------------- xs = bf16(lrelu(bn(c) + res)) channel-last ----------------
__global__ __launch_bounds__(256) void k_bn_xs(const float* __restrict__ c,
    const float* __restrict__ st, const float* __restrict__ g, const float* __restrict__ be,
    const float* __restrict__ res, unsigned short* __restrict__ xs){
  int i = blockIdx.x*256 + threadIdx.x;
  if (i >= NEL) return;
  int ch = i & 127;
  float v = (c[i] - st[ch*2]) * st[ch*2+1] * g[ch] + be[ch] + res[i];
  xs[i] = f2bf(lrelu(v));
}

// ---------------- final: lrelu(bn_t(c3)+bn_rt(c4)), cl -> NCHW via LDS ----------------
__global__ __launch_bounds__(256) void k_final_cl(const float* __restrict__ c3,
    const float* __restrict__ st3, const float* __restrict__ g3, const float* __restrict__ be3,
    const float* __restrict__ c4, const float* __restrict__ st4, const float* __restrict__ g4,
    const float* __restrict__ be4, float* __restrict__ out){
  __shared__ float tile[64][153];
  int tid = threadIdx.x;
  int t = blockIdx.x, n = blockIdx.y;
  size_t pixb = (size_t)(n*TT + t)*VV;
  for (int ch0=0; ch0<OO; ch0+=64){
    __syncthreads();
    for (int idx=tid; idx<VV*64; idx+=256){
      int v = idx >> 6, cc = idx & 63;
      int ch = ch0 + cc;
      float a = (c3[(pixb+v)*OO + ch] - st3[ch*2]) * st3[ch*2+1] * g3[ch] + be3[ch];
      float b = (c4[(pixb+v)*OO + ch] - st4[ch*2]) * st4[ch*2+1] * g4[ch] + be4[ch];
      tile[cc][v] = lrelu(a + b);
    }
    __syncthreads();
    for (int idx=tid; idx<64*VV; idx+=256){
      int cc = idx / VV, v = idx - cc*VV;
      out[((size_t)(n*OO + ch0 + cc)*TT + t)*VV + v] = tile[cc][v];
    }
  }
}

extern "C" void kernel_launch(void* const* d_in, const int* in_sizes, int n_in,
                              void* d_out, int out_size, void* d_ws, size_t ws_size,
                              hipStream_t stream) {
  const float* x        = (const float*)d_in[0];
  const float* W_qkv    = (const float*)d_in[1];
  const float* b_qkv    = (const float*)d_in[2];
  const float* alphas   = (const float*)d_in[3];
  const float* att0s    = (const float*)d_in[4];
  const float* degree_emb = (const float*)d_in[5];
  const float* spatial_emb = (const float*)d_in[6];
  const float* W_out    = (const float*)d_in[7];
  const float* g_out    = (const float*)d_in[9];
  const float* be_out   = (const float*)d_in[10];
  const float* W_ff     = (const float*)d_in[11];
  const float* g_ff     = (const float*)d_in[13];
  const float* be_ff    = (const float*)d_in[14];
  const float* W_t      = (const float*)d_in[15];
  const float* g_t      = (const float*)d_in[17];
  const float* be_t     = (const float*)d_in[18];
  const float* W_rs     = (const float*)d_in[19];
  const float* g_rs     = (const float*)d_in[21];
  const float* be_rs    = (const float*)d_in[22];
  const float* W_rt     = (const float*)d_in[23];
  const float* g_rt     = (const float*)d_in[25];
  const float* be_rt    = (const float*)d_in[26];
  const int* all_degree = (const int*)d_in[27];
  const int* spatial_pos= (const int*)d_in[28];

  char* ws = (char*)d_ws;
  // region0 @0 (49.2MB): qkvcl -> ycl
  // P @49.2M (24.6MB): c1 -> c2 -> c3
  // Q @73.8M (24.6MB): attT -> rs_raw/rsb -> c4
  // R @98.4M (12.3MB): xclr -> xs1
  // S @110.7M (12.3MB): xbf (padded 160) -> xs2
  // xcl @123.0M (6.15MB)
  // weights @129.2M ; bias @130.2M ; stats @130.25M ; psum @130.26M
  unsigned short* qkvcl = (unsigned short*)(ws + 0);
  unsigned short* ycl   = qkvcl;
  float* P = (float*)(ws + 49200000);
  float* c1 = P, *c2 = P, *c3 = P;
  unsigned short* attT = (unsigned short*)(ws + 73800000);
  float* rsb = (float*)(ws + 73800000);
  float* c4  = (float*)(ws + 73800000);
  unsigned short* xclr = (unsigned short*)(ws + 98400000);
  unsigned short* xs1  = (unsigned short*)(ws + 98400000);
  unsigned short* xbf  = (unsigned short*)(ws + 110700000);
  unsigned short* xs2  = (unsigned short*)(ws + 110700000);
  unsigned short* xcl  = (unsigned short*)(ws + 123000000);
  unsigned short* Wq_sw  = (unsigned short*)(ws + 129200000);
  unsigned short* Wout_sw= (unsigned short*)(ws + 129200000 + 65536);
  unsigned short* Wff_sw = (unsigned short*)(ws + 129200000 + 720896);
  unsigned short* Wrt_sw = (unsigned short*)(ws + 129200000 + 753664);
  unsigned short* Wt_sw  = (unsigned short*)(ws + 129200000 + 786432);
  unsigned short* Wrs_sw = (unsigned short*)(ws + 129200000 + 884736);
  float* bias  = (float*)(ws + 130200000);
  float* stats = (float*)(ws + 130250000);
  float* psum  = (float*)(ws + 130260000);
  float* out = (float*)d_out;

  k_bias<<<dim3(38), 256, 0, stream>>>(degree_emb, all_degree, bias);
  k_wprep_gen<<<16, 256, 0, stream>>>(W_qkv, Wq_sw, 32, 2, 64, 1, 0);
  for (int kv=0; kv<5; kv++)
    k_wprep_gen<<<32, 256, 0, stream>>>(W_out, Wout_sw + kv*65536, 8, 16, 2560, 5, kv);
  k_wprep_gen<<<8, 256, 0, stream>>>(W_ff, Wff_sw, 8, 4, 128, 1, 0);
  k_wprep_gen<<<8, 256, 0, stream>>>(W_rt, Wrt_sw, 8, 4, 128, 1, 0);
  for (int kt=0; kt<3; kt++)
    k_wprep_gen<<<8, 256, 0, stream>>>(W_t, Wt_sw + kt*16384, 8, 4, 384, 3, kt);
  k_wprep_gen<<<4, 256, 0, stream>>>(W_rs, Wrs_sw, 8, 2, 64, 1, 0);

  k_xprep<<<dim3(20,16), 256, 0, stream>>>(x, bias, xbf, xcl, xclr);
  k_qkv_mfma<<<1500, 256, 0, stream>>>(xcl, Wq_sw, b_qkv, qkvcl);
  k_att_mfma<<<dim3(8,16), 256, 0, stream>>>(qkvcl, alphas, att0s, spatial_emb, spatial_pos, attT);
  k_yapply_mfma<<<dim3(20,16), 256, 0, stream>>>(attT, xbf, ycl);

  // residual branch (after attT is dead; writes Q region)
  k_conv1x1_mfma<<<750, 256, 0, stream>>>(xclr, Wrs_sw, rsb, 2);
  k_stats1<<<125, 256, 0, stream>>>(rsb, psum);
  k_stats2<<<1, 128, 0, stream>>>(psum, stats + 0);
  k_bn_rs<<<24000, 256, 0, stream>>>(rsb, stats + 0, g_rs, be_rs);

  k_conv_out_mfma<<<dim3(20,16), 256, 0, stream>>>(ycl, Wout_sw, c1);
  k_stats1<<<125, 256, 0, stream>>>(c1, psum);
  k_stats2<<<1, 128, 0, stream>>>(psum, stats + 256);
  k_bn_xs<<<24000, 256, 0, stream>>>(c1, stats + 256, g_out, be_out, rsb, xs1);

  k_conv1x1_mfma<<<750, 256, 0, stream>>>(xs1, Wff_sw, c2, 4);
  k_stats1<<<125, 256, 0, stream>>>(c2, psum);
  k_stats2<<<1, 128, 0, stream>>>(psum, stats + 512);
  k_bn_xs<<<24000, 256, 0, stream>>>(c2, stats + 512, g_ff, be_ff, rsb, xs2);

  k_conv_t_mfma<<<dim3(20,16), 256, 0, stream>>>(xs2, Wt_sw, c3);
  k_conv1x1_mfma<<<750, 256, 0, stream>>>(xs2, Wrt_sw, c4, 4);
  k_stats1<<<125, 256, 0, stream>>>(c3, psum);
  k_stats2<<<1, 128, 0, stream>>>(psum, stats + 768);
  k_stats1<<<125, 256, 0, stream>>>(c4, psum);
  k_stats2<<<1, 128, 0, stream>>>(psum, stats + 1024);
  k_final_cl<<<dim3(20,16), 256, 0, stream>>>(c3, stats + 768, g_t, be_t,
                                              c4, stats + 1024, g_rt, be_rt, out);
}

// Round 4
// 467.041 us; speedup vs baseline: 4.7475x; 1.2415x over previous
//
#include <hip/hip_runtime.h>

#define NN 16
#define CC 64
#define TT 20
#define VV 150
#define HH 8
#define DD 32
#define OO 128
#define TV 3000
#define QCH 512
#define NPIX 48000
#define NEL 6144000  // N*O*T*V

using bf16x8 = __attribute__((ext_vector_type(8))) short;
using f32x4  = __attribute__((ext_vector_type(4))) float;

__device__ __forceinline__ float bf2f(unsigned short u){
  union { unsigned int i; float f; } x; x.i = ((unsigned int)u) << 16; return x.f;
}
__device__ __forceinline__ unsigned short f2bf(float f){
  union { float f; unsigned int i; } x; x.f = f;
  unsigned int r = x.i + 0x7fffu + ((x.i >> 16) & 1u);
  return (unsigned short)(r >> 16);
}
__device__ __forceinline__ float lrelu(float v){ return v > 0.f ? v : 0.1f*v; }

// ---------------- bias table ----------------
__global__ __launch_bounds__(256) void k_bias(const float* __restrict__ degree_emb,
    const int* __restrict__ all_degree, float* __restrict__ bias){
  int i = blockIdx.x*256 + threadIdx.x;
  if (i >= CC*VV) return;
  int c = i / VV, v = i % VV;
  float freq = __expf(-(float)(c >> 1) * 0.2878231366f);
  float arg = (float)v * freq;
  float pe = (c & 1) ? cosf(arg) : sinf(arg);
  int dgi = all_degree[v % 25];
  bias[i] = pe + degree_emb[dgi*CC + c];
}

// ---------------- generic A-fragment swizzler ----------------
__global__ __launch_bounds__(256) void k_wprep_gen(const float* __restrict__ W,
    unsigned short* __restrict__ out, int MT, int KT, int rs, int ks, int koff){
  int g = blockIdx.x*256 + threadIdx.x;
  if (g >= MT*KT*64) return;
  int lane = g & 63;
  int f = g >> 6;
  int mt = f % MT, kk = f / MT;
  int row = mt*16 + (lane & 15);
  int kb = kk*32 + (lane >> 4)*8;
  unsigned int pk[4];
  #pragma unroll
  for (int j=0;j<4;j++){
    unsigned short a = f2bf(W[row*rs + (kb+2*j)*ks + koff]);
    unsigned short b = f2bf(W[row*rs + (kb+2*j+1)*ks + koff]);
    pk[j] = (unsigned int)a | ((unsigned int)b << 16);
  }
  unsigned int* dst = (unsigned int*)(out + (size_t)g*8);
  #pragma unroll
  for (int j=0;j<4;j++) dst[j] = pk[j];
}

// ---------------- x prep ----------------
__global__ __launch_bounds__(256) void k_xprep(const float* __restrict__ x,
    const float* __restrict__ bias, unsigned short* __restrict__ xbf,
    unsigned short* __restrict__ xcl, unsigned short* __restrict__ xclr){
  __shared__ float xl[64][153];
  int tid = threadIdx.x;
  int t = blockIdx.x, n = blockIdx.y;
  for (int idx=tid; idx<64*160; idx+=256){
    int c = idx/160, v = idx - c*160;
    float xv = 0.f;
    if (v < VV){
      xv = x[((size_t)(n*CC+c)*TT + t)*VV + v];
      xl[c][v] = xv;
    }
    xbf[((size_t)(n*CC+c)*TT + t)*160 + v] = f2bf(xv);
  }
  __syncthreads();
  size_t pixb = (size_t)(n*TT + t)*VV;
  for (int idx=tid; idx<4800; idx+=256){
    int v = idx >> 5, c2 = (idx & 31)*2;
    float a0 = xl[c2][v],   a1 = xl[c2+1][v];
    unsigned int raw = (unsigned int)f2bf(a0) | ((unsigned int)f2bf(a1) << 16);
    float b0 = a0 + bias[c2*VV + v], b1 = a1 + bias[(c2+1)*VV + v];
    unsigned int bi = (unsigned int)f2bf(b0) | ((unsigned int)f2bf(b1) << 16);
    *(unsigned int*)(xclr + (pixb + v)*CC + c2) = raw;
    *(unsigned int*)(xcl  + (pixb + v)*CC + c2) = bi;
  }
}

// ---------------- qkv MFMA: M=512, K=64 ----------------
__global__ __launch_bounds__(256) void k_qkv_mfma(const unsigned short* __restrict__ xcl,
    const unsigned short* __restrict__ Wsw, const float* __restrict__ bq,
    unsigned short* __restrict__ qkv){
  int tid = threadIdx.x, wave = tid >> 6, lane = tid & 63;
  int l15 = lane & 15, lhi = lane >> 4;
  int pix0 = blockIdx.x*32;
  f32x4 acc[8][2];
  #pragma unroll
  for (int m=0;m<8;m++){ acc[m][0] = f32x4{0,0,0,0}; acc[m][1] = f32x4{0,0,0,0}; }
  #pragma unroll
  for (int kk=0;kk<2;kk++){
    bf16x8 bfr[2];
    #pragma unroll
    for (int q=0;q<2;q++)
      bfr[q] = *(const bf16x8*)(xcl + (size_t)(pix0 + q*16 + l15)*CC + kk*32 + lhi*8);
    #pragma unroll
    for (int m=0;m<8;m++){
      bf16x8 afr = *(const bf16x8*)(Wsw + ((size_t)(kk*32 + wave*8 + m)*64 + lane)*8);
      acc[m][0] = __builtin_amdgcn_mfma_f32_16x16x32_bf16(afr, bfr[0], acc[m][0], 0,0,0);
      acc[m][1] = __builtin_amdgcn_mfma_f32_16x16x32_bf16(afr, bfr[1], acc[m][1], 0,0,0);
    }
  }
  #pragma unroll
  for (int m=0;m<8;m++){
    int o0 = (wave*8 + m)*16 + lhi*4;
    float b0 = bq[o0], b1 = bq[o0+1], b2 = bq[o0+2], b3 = bq[o0+3];
    #pragma unroll
    for (int q=0;q<2;q++){
      int pix = pix0 + q*16 + l15;
      uint2 pk;
      pk.x = (unsigned int)f2bf(acc[m][q][0]+b0) | ((unsigned int)f2bf(acc[m][q][1]+b1) << 16);
      pk.y = (unsigned int)f2bf(acc[m][q][2]+b2) | ((unsigned int)f2bf(acc[m][q][3]+b3) << 16);
      *(uint2*)(qkv + (size_t)pix*QCH + o0) = pk;
    }
  }
}

// ---------------- att MFMA: grid (5 vt, 8 h, 16 n); wave = 5 u-tiles x 1 v-tile ----------------
__global__ __launch_bounds__(256) void k_att_mfma(const unsigned short* __restrict__ qkv,
    const float* __restrict__ alphas, const float* __restrict__ att0s,
    const float* __restrict__ sp_emb, const int* __restrict__ sp_pos,
    unsigned short* __restrict__ attT){
  int tid = threadIdx.x, wave = tid >> 6, lane = tid & 63;
  int l15 = lane & 15, lhi = lane >> 4;
  int vt = blockIdx.x, h = blockIdx.y, n = blockIdx.z;
  int uhalf = wave & 1, vsel = wave >> 1;
  int v = (vt*2 + vsel)*16 + l15;     // < 160
  f32x4 acc[5];
  #pragma unroll
  for (int ui=0;ui<5;ui++) acc[ui] = f32x4{0,0,0,0};
  for (int t=0;t<TT;t++){
    size_t rowb = (size_t)(n*TT + t)*VV;
    bf16x8 bfr = bf16x8{};
    if (v < VV) bfr = *(const bf16x8*)(qkv + (rowb + v)*QCH + 256 + h*DD + lhi*8);
    #pragma unroll
    for (int ui=0;ui<5;ui++){
      int u = (uhalf*5+ui)*16 + l15;
      bf16x8 afr = bf16x8{};
      if (u < VV) afr = *(const bf16x8*)(qkv + (rowb + u)*QCH + h*DD + lhi*8);
      acc[ui] = __builtin_amdgcn_mfma_f32_16x16x32_bf16(afr, bfr, acc[ui], 0,0,0);
    }
  }
  float al = alphas[h];
  #pragma unroll
  for (int ui=0;ui<5;ui++){
    int u0 = (uhalf*5+ui)*16 + lhi*4;
    unsigned short hv[4];
    #pragma unroll
    for (int r=0;r<4;r++){
      int u = u0 + r;
      unsigned short val = 0;
      if (u < VV && v < VV){
        float gv = tanhf(acc[ui][r]*(1.f/640.f))*al
                 + att0s[((size_t)h*VV + u)*VV + v]
                 + sp_emb[sp_pos[u*VV + v]*HH + h];
        val = f2bf(gv);
      }
      hv[r] = val;
    }
    uint2 pk;
    pk.x = (unsigned int)hv[0] | ((unsigned int)hv[1] << 16);
    pk.y = (unsigned int)hv[2] | ((unsigned int)hv[3] << 16);
    *(uint2*)(attT + ((size_t)((n*HH+h)*160) + v)*160 + u0) = pk;
  }
}

// ---------------- yapply MFMA: grid (8 h, 20 t, 16 n); wave = 5 v-tiles x 2 c-tiles ----------------
__global__ __launch_bounds__(256) void k_yapply_mfma(const unsigned short* __restrict__ attT,
    const unsigned short* __restrict__ xbf, unsigned short* __restrict__ ycl){
  int tid = threadIdx.x, wave = tid >> 6, lane = tid & 63;
  int l15 = lane & 15, lhi = lane >> 4;
  int h = blockIdx.x, t = blockIdx.y, n = blockIdx.z;
  int vtb = (wave & 1)*5, ctb = (wave >> 1)*2;
  f32x4 acc[5][2];
  #pragma unroll
  for (int vi=0;vi<5;vi++){ acc[vi][0] = f32x4{0,0,0,0}; acc[vi][1] = f32x4{0,0,0,0}; }
  #pragma unroll
  for (int kk=0;kk<5;kk++){
    bf16x8 bfr[2];
    #pragma unroll
    for (int ci=0;ci<2;ci++){
      int c = (ctb+ci)*16 + l15;
      bfr[ci] = *(const bf16x8*)(xbf + ((size_t)(n*CC+c)*TT + t)*160 + kk*32 + lhi*8);
    }
    #pragma unroll
    for (int vi=0;vi<5;vi++){
      int v = (vtb+vi)*16 + l15;
      bf16x8 afr = *(const bf16x8*)(attT + ((size_t)((n*HH+h)*160) + v)*160 + kk*32 + lhi*8);
      #pragma unroll
      for (int ci=0;ci<2;ci++)
        acc[vi][ci] = __builtin_amdgcn_mfma_f32_16x16x32_bf16(afr, bfr[ci], acc[vi][ci], 0,0,0);
    }
  }
  size_t pixb = (size_t)(n*TT + t)*VV;
  #pragma unroll
  for (int vi=0;vi<5;vi++){
    int v0 = (vtb+vi)*16 + lhi*4;
    #pragma unroll
    for (int ci=0;ci<2;ci++){
      int c = (ctb+ci)*16 + l15;
      #pragma unroll
      for (int r=0;r<4;r++){
        int v = v0 + r;
        if (v < VV)
          ycl[(pixb + v)*QCH + h*CC + c] = f2bf(acc[vi][ci][r]);
      }
    }
  }
}

// ---------------- conv_out MFMA: grid (5 vt, 20 t, 16 n); wave = 4 m-tiles x 1 n-tile ----------------
__global__ __launch_bounds__(256) void k_conv_out_mfma(const unsigned short* __restrict__ ycl,
    const unsigned short* __restrict__ Wsw, float* __restrict__ out){
  int tid = threadIdx.x, wave = tid >> 6, lane = tid & 63;
  int l15 = lane & 15, lhi = lane >> 4;
  int vt = blockIdx.x, t = blockIdx.y, n = blockIdx.z;
  int mtb = (wave & 1)*4;
  int ntile = wave >> 1;
  int vbase = vt*32 + ntile*16 + l15 - 2;
  f32x4 acc[4];
  #pragma unroll
  for (int m=0;m<4;m++) acc[m] = f32x4{0,0,0,0};
  const unsigned short* yb = ycl + (size_t)(n*TT + t)*VV*QCH + lhi*8;
  for (int kk=0; kk<16; kk++){
    bf16x8 bfr[5];
    #pragma unroll
    for (int kv=0; kv<5; kv++){
      int v = vbase + kv;
      bfr[kv] = bf16x8{};
      if (v >= 0 && v < VV)
        bfr[kv] = *(const bf16x8*)(yb + (size_t)v*QCH + kk*32);
    }
    #pragma unroll
    for (int kv=0; kv<5; kv++){
      #pragma unroll
      for (int m=0;m<4;m++){
        bf16x8 afr = *(const bf16x8*)(Wsw + (size_t)kv*65536 + ((size_t)(kk*8 + mtb + m)*64 + lane)*8);
        acc[m] = __builtin_amdgcn_mfma_f32_16x16x32_bf16(afr, bfr[kv], acc[m], 0,0,0);
      }
    }
  }
  int v = vt*32 + ntile*16 + l15;
  if (v < VV){
    #pragma unroll
    for (int m=0;m<4;m++){
      int o0 = (mtb+m)*16 + lhi*4;
      float4 val = make_float4(acc[m][0], acc[m][1], acc[m][2], acc[m][3]);
      *(float4*)(out + ((size_t)(n*TT+t)*VV + v)*OO + o0) = val;
    }
  }
}

// ---------------- 1x1 conv MFMA: grid 1500; wave = 4 m-tiles x 1 n-tile ----------------
__global__ __launch_bounds__(256) void k_conv1x1_mfma(const unsigned short* __restrict__ in,
    const unsigned short* __restrict__ Wsw, float* __restrict__ out, int KT){
  int tid = threadIdx.x, wave = tid >> 6, lane = tid & 63;
  int l15 = lane & 15, lhi = lane >> 4;
  int mtb = (wave & 1)*4;
  int ntile = wave >> 1;
  int pix = blockIdx.x*32 + ntile*16 + l15;
  int KD = KT*32;
  f32x4 acc[4];
  #pragma unroll
  for (int m=0;m<4;m++) acc[m] = f32x4{0,0,0,0};
  for (int kk=0; kk<KT; kk++){
    bf16x8 bfr = *(const bf16x8*)(in + (size_t)pix*KD + kk*32 + lhi*8);
    #pragma unroll
    for (int m=0;m<4;m++){
      bf16x8 afr = *(const bf16x8*)(Wsw + ((size_t)(kk*8 + mtb + m)*64 + lane)*8);
      acc[m] = __builtin_amdgcn_mfma_f32_16x16x32_bf16(afr, bfr, acc[m], 0,0,0);
    }
  }
  #pragma unroll
  for (int m=0;m<4;m++){
    int o0 = (mtb+m)*16 + lhi*4;
    float4 val = make_float4(acc[m][0], acc[m][1], acc[m][2], acc[m][3]);
    *(float4*)(out + (size_t)pix*OO + o0) = val;
  }
}

// ---------------- fused conv_t (3x1) + conv_rt (1x1): grid (5 vt, 20 t, 16 n) ----------------
__global__ __launch_bounds__(256) void k_conv_trt_mfma(const unsigned short* __restrict__ in,
    const unsigned short* __restrict__ Wt_sw, const unsigned short* __restrict__ Wrt_sw,
    float* __restrict__ outT, float* __restrict__ outR){
  int tid = threadIdx.x, wave = tid >> 6, lane = tid & 63;
  int l15 = lane & 15, lhi = lane >> 4;
  int vt = blockIdx.x, t = blockIdx.y, n = blockIdx.z;
  int mtb = (wave & 1)*4;
  int ntile = wave >> 1;
  int v = vt*32 + ntile*16 + l15;
  bool vok = v < VV;
  f32x4 acc[4], accr[4];
  #pragma unroll
  for (int m=0;m<4;m++){ acc[m] = f32x4{0,0,0,0}; accr[m] = f32x4{0,0,0,0}; }
  #pragma unroll
  for (int kt=0; kt<3; kt++){
    int tt = t + kt - 1;
    if (tt < 0 || tt >= TT) continue;
    const unsigned short* ib = in + ((size_t)(n*TT + tt)*VV + v)*OO + lhi*8;
    #pragma unroll
    for (int kk=0; kk<4; kk++){
      bf16x8 bfr = bf16x8{};
      if (vok) bfr = *(const bf16x8*)(ib + kk*32);
      #pragma unroll
      for (int m=0;m<4;m++){
        bf16x8 afr = *(const bf16x8*)(Wt_sw + (size_t)kt*16384 + ((size_t)(kk*8 + mtb + m)*64 + lane)*8);
        acc[m] = __builtin_amdgcn_mfma_f32_16x16x32_bf16(afr, bfr, acc[m], 0,0,0);
      }
      if (kt == 1){
        #pragma unroll
        for (int m=0;m<4;m++){
          bf16x8 afr = *(const bf16x8*)(Wrt_sw + ((size_t)(kk*8 + mtb + m)*64 + lane)*8);
          accr[m] = __builtin_amdgcn_mfma_f32_16x16x32_bf16(afr, bfr, accr[m], 0,0,0);
        }
      }
    }
  }
  if (vok){
    size_t pb = ((size_t)(n*TT+t)*VV + v)*OO;
    #pragma unroll
    for (int m=0;m<4;m++){
      int o0 = (mtb+m)*16 + lhi*4;
      *(float4*)(outT + pb + o0) = make_float4(acc[m][0], acc[m][1], acc[m][2], acc[m][3]);
      *(float4*)(outR + pb + o0) = make_float4(accr[m][0], accr[m][1], accr[m][2], accr[m][3]);
    }
  }
}

// ---------------- stats stage 1 ----------------
__global__ __launch_bounds__(256) void k_stats1(const float* __restrict__ in, float* __restrict__ psum){
  int tid = threadIdx.x, blk = blockIdx.x;
  int ch = tid & 127, half = tid >> 7;
  float s = 0.f, s2 = 0.f;
  for (int i=0;i<192;i++){
    int p = blk*384 + i*2 + half;
    float v = in[(size_t)p*OO + ch];
    s += v; s2 += v*v;
  }
  int idx = (blk*2 + half)*OO + ch;
  psum[idx] = s;
  psum[32000 + idx] = s2;
}

// ---------------- stats stage 2: one block per channel ----------------
__global__ __launch_bounds__(64) void k_stats2(const float* __restrict__ psum, float* __restrict__ st){
  int ch = blockIdx.x, tid = threadIdx.x;
  float s = 0.f, s2 = 0.f;
  for (int i=tid;i<250;i+=64){
    s  += psum[i*OO + ch];
    s2 += psum[32000 + i*OO + ch];
  }
  #pragma unroll
  for (int off=32; off; off>>=1){ s += __shfl_down(s, off); s2 += __shfl_down(s2, off); }
  if (tid == 0){
    float m = s * (1.f/48000.f);
    float var = s2 * (1.f/48000.f) - m*m;
    st[ch*2] = m;
    st[ch*2+1] = rsqrtf(var + 1e-5f);
  }
}

// ---------------- BN in-place fp32 channel-last (residual branch), x4 vectorized ----------------
__global__ __launch_bounds__(256) void k_bn_rs(float* __restrict__ buf,
    const float* __restrict__ st, const float* __restrict__ g, const float* __restrict__ be){
  int i = (blockIdx.x*256 + threadIdx.x)*4;
  if (i >= NEL) return;
  int ch = i & 127;
  float4 v = *(float4*)(buf + i);
  v.x = (v.x - st[ch*2+0]) * st[ch*2+1] * g[ch+0] + be[ch+0];
  v.y = (v.y - st[ch*2+2]) * st[ch*2+3] * g[ch+1] + be[ch+1];
  v.z = (v.z - st[ch*2+4]) * st[ch*2+5] * g[ch+2] + be[ch+2];
  v.w = (v.w - st[ch*2+6]) * st[ch*2+7] * g[ch+3] + be[ch+3];
  *(float4*)(buf + i) = v;
}

// ---------------- xs = bf16(lrelu(bn(c) + res)), x4 vectorized ----------------
__global__ __launch_bounds__(256) void k_bn_xs(const float* __restrict__ c,
    const float* __restrict__ st, const float* __restrict__ g, const float* __restrict__ be,
    const float* __restrict__ res, unsigned short* __restrict__ xs){
  int i = (blockIdx.x*256 + threadIdx.x)*4;
  if (i >= NEL) return;
  int ch = i & 127;
  float4 v = *(const float4*)(c + i);
  float4 r = *(const float4*)(res + i);
  float o0 = lrelu((v.x - st[ch*2+0]) * st[ch*2+1] * g[ch+0] + be[ch+0] + r.x);
  float o1 = lrelu((v.y - st[ch*2+2]) * st[ch*2+3] * g[ch+1] + be[ch+1] + r.y);
  float o2 = lrelu((v.z - st[ch*2+4]) * st[ch*2+5] * g[ch+2] + be[ch+2] + r.z);
  float o3 = lrelu((v.w - st[ch*2+6]) * st[ch*2+7] * g[ch+3] + be[ch+3] + r.w);
  uint2 pk;
  pk.x = (unsigned int)f2bf(o0) | ((unsigned int)f2bf(o1) << 16);
  pk.y = (unsigned int)f2bf(o2) | ((unsigned int)f2bf(o3) << 16);
  *(uint2*)(xs + i) = pk;
}

// ---------------- final: lrelu(bn_t(c3)+bn_rt(c4)), cl -> NCHW ----------------
__global__ __launch_bounds__(256) void k_final_cl(const float* __restrict__ c3,
    const float* __restrict__ st3, const float* __restrict__ g3, const float* __restrict__ be3,
    const float* __restrict__ c4, const float* __restrict__ st4, const float* __restrict__ g4,
    const float* __restrict__ be4, float* __restrict__ out){
  __shared__ float tile[64][153];
  int tid = threadIdx.x;
  int t = blockIdx.x, n = blockIdx.y;
  size_t pixb = (size_t)(n*TT + t)*VV;
  for (int ch0=0; ch0<OO; ch0+=64){
    __syncthreads();
    for (int idx=tid; idx<VV*64; idx+=256){
      int v = idx >> 6, cc = idx & 63;
      int ch = ch0 + cc;
      float a = (c3[(pixb+v)*OO + ch] - st3[ch*2]) * st3[ch*2+1] * g3[ch] + be3[ch];
      float b = (c4[(pixb+v)*OO + ch] - st4[ch*2]) * st4[ch*2+1] * g4[ch] + be4[ch];
      tile[cc][v] = lrelu(a + b);
    }
    __syncthreads();
    for (int idx=tid; idx<64*VV; idx+=256){
      int cc = idx / VV, v = idx - cc*VV;
      out[((size_t)(n*OO + ch0 + cc)*TT + t)*VV + v] = tile[cc][v];
    }
  }
}

extern "C" void kernel_launch(void* const* d_in, const int* in_sizes, int n_in,
                              void* d_out, int out_size, void* d_ws, size_t ws_size,
                              hipStream_t stream) {
  const float* x        = (const float*)d_in[0];
  const float* W_qkv    = (const float*)d_in[1];
  const float* b_qkv    = (const float*)d_in[2];
  const float* alphas   = (const float*)d_in[3];
  const float* att0s    = (const float*)d_in[4];
  const float* degree_emb = (const float*)d_in[5];
  const float* spatial_emb = (const float*)d_in[6];
  const float* W_out    = (const float*)d_in[7];
  const float* g_out    = (const float*)d_in[9];
  const float* be_out   = (const float*)d_in[10];
  const float* W_ff     = (const float*)d_in[11];
  const float* g_ff     = (const float*)d_in[13];
  const float* be_ff    = (const float*)d_in[14];
  const float* W_t      = (const float*)d_in[15];
  const float* g_t      = (const float*)d_in[17];
  const float* be_t     = (const float*)d_in[18];
  const float* W_rs     = (const float*)d_in[19];
  const float* g_rs     = (const float*)d_in[21];
  const float* be_rs    = (const float*)d_in[22];
  const float* W_rt     = (const float*)d_in[23];
  const float* g_rt     = (const float*)d_in[25];
  const float* be_rt    = (const float*)d_in[26];
  const int* all_degree = (const int*)d_in[27];
  const int* spatial_pos= (const int*)d_in[28];

  char* ws = (char*)d_ws;
  unsigned short* qkvcl = (unsigned short*)(ws + 0);
  unsigned short* ycl   = qkvcl;
  float* P = (float*)(ws + 49200000);
  float* c1 = P, *c2 = P, *c3 = P;
  unsigned short* attT = (unsigned short*)(ws + 73800000);
  float* rsb = (float*)(ws + 73800000);
  float* c4  = (float*)(ws + 73800000);
  unsigned short* xclr = (unsigned short*)(ws + 98400000);
  unsigned short* xs1  = (unsigned short*)(ws + 98400000);
  unsigned short* xbf  = (unsigned short*)(ws + 110700000);
  unsigned short* xs2  = (unsigned short*)(ws + 110700000);
  unsigned short* xcl  = (unsigned short*)(ws + 123000000);
  unsigned short* Wq_sw  = (unsigned short*)(ws + 129200000);
  unsigned short* Wout_sw= (unsigned short*)(ws + 129200000 + 65536);
  unsigned short* Wff_sw = (unsigned short*)(ws + 129200000 + 720896);
  unsigned short* Wrt_sw = (unsigned short*)(ws + 129200000 + 753664);
  unsigned short* Wt_sw  = (unsigned short*)(ws + 129200000 + 786432);
  unsigned short* Wrs_sw = (unsigned short*)(ws + 129200000 + 884736);
  float* bias  = (float*)(ws + 130200000);
  float* stats = (float*)(ws + 130250000);
  float* psum  = (float*)(ws + 130260000);
  float* out = (float*)d_out;

  k_bias<<<dim3(38), 256, 0, stream>>>(degree_emb, all_degree, bias);
  k_wprep_gen<<<16, 256, 0, stream>>>(W_qkv, Wq_sw, 32, 2, 64, 1, 0);
  for (int kv=0; kv<5; kv++)
    k_wprep_gen<<<32, 256, 0, stream>>>(W_out, Wout_sw + kv*65536, 8, 16, 2560, 5, kv);
  k_wprep_gen<<<8, 256, 0, stream>>>(W_ff, Wff_sw, 8, 4, 128, 1, 0);
  k_wprep_gen<<<8, 256, 0, stream>>>(W_rt, Wrt_sw, 8, 4, 128, 1, 0);
  for (int kt=0; kt<3; kt++)
    k_wprep_gen<<<8, 256, 0, stream>>>(W_t, Wt_sw + kt*16384, 8, 4, 384, 3, kt);
  k_wprep_gen<<<4, 256, 0, stream>>>(W_rs, Wrs_sw, 8, 2, 64, 1, 0);

  k_xprep<<<dim3(20,16), 256, 0, stream>>>(x, bias, xbf, xcl, xclr);
  k_qkv_mfma<<<1500, 256, 0, stream>>>(xcl, Wq_sw, b_qkv, qkvcl);
  k_att_mfma<<<dim3(5,8,16), 256, 0, stream>>>(qkvcl, alphas, att0s, spatial_emb, spatial_pos, attT);
  k_yapply_mfma<<<dim3(8,20,16), 256, 0, stream>>>(attT, xbf, ycl);

  k_conv1x1_mfma<<<1500, 256, 0, stream>>>(xclr, Wrs_sw, rsb, 2);
  k_stats1<<<125, 256, 0, stream>>>(rsb, psum);
  k_stats2<<<128, 64, 0, stream>>>(psum, stats + 0);
  k_bn_rs<<<6000, 256, 0, stream>>>(rsb, stats + 0, g_rs, be_rs);

  k_conv_out_mfma<<<dim3(5,20,16), 256, 0, stream>>>(ycl, Wout_sw, c1);
  k_stats1<<<125, 256, 0, stream>>>(c1, psum);
  k_stats2<<<128, 64, 0, stream>>>(psum, stats + 256);
  k_bn_xs<<<6000, 256, 0, stream>>>(c1, stats + 256, g_out, be_out, rsb, xs1);

  k_conv1x1_mfma<<<1500, 256, 0, stream>>>(xs1, Wff_sw, c2, 4);
  k_stats1<<<125, 256, 0, stream>>>(c2, psum);
  k_stats2<<<128, 64, 0, stream>>>(psum, stats + 512);
  k_bn_xs<<<6000, 256, 0, stream>>>(c2, stats + 512, g_ff, be_ff, rsb, xs2);

  k_conv_trt_mfma<<<dim3(5,20,16), 256, 0, stream>>>(xs2, Wt_sw, Wrt_sw, c3, c4);
  k_stats1<<<125, 256, 0, stream>>>(c3, psum);
  k_stats2<<<128, 64, 0, stream>>>(psum, stats + 768);
  k_stats1<<<125, 256, 0, stream>>>(c4, psum);
  k_stats2<<<128, 64, 0, stream>>>(psum, stats + 1024);
  k_final_cl<<<dim3(20,16), 256, 0, stream>>>(c3, stats + 768, g_t, be_t,
                                              c4, stats + 1024, g_rt, be_rt, out);
}

// Round 5
// 408.646 us; speedup vs baseline: 5.4259x; 1.1429x over previous
//
#include <hip/hip_runtime.h>

#define NN 16
#define CC 64
#define TT 20
#define VV 150
#define HH 8
#define DD 32
#define OO 128
#define TV 3000
#define QCH 512
#define NPIX 48000
#define NEL 6144000  // N*O*T*V

using bf16x8 = __attribute__((ext_vector_type(8))) short;
using f32x4  = __attribute__((ext_vector_type(4))) float;

__device__ __forceinline__ unsigned short f2bf(float f){
  union { float f; unsigned int i; } x; x.f = f;
  unsigned int r = x.i + 0x7fffu + ((x.i >> 16) & 1u);
  return (unsigned short)(r >> 16);
}
__device__ __forceinline__ float lrelu(float v){ return v > 0.f ? v : 0.1f*v; }

// ---------------- merged weight pre-swizzle: 12 jobs, one launch ----------------
struct WprepJob { const float* W; unsigned short* dst; int MT, KT, rs, ks, koff, base; };
struct WprepArgs { WprepJob j[12]; };

__global__ __launch_bounds__(256) void k_wprep_all(WprepArgs a, int total){
  int g = blockIdx.x*256 + threadIdx.x;
  if (g >= total) return;
  int s = 0;
  #pragma unroll
  for (int q=1; q<12; q++) if (g >= a.j[q].base) s = q;
  const WprepJob jb = a.j[s];
  int gg = g - jb.base;
  int lane = gg & 63;
  int f = gg >> 6;
  int mt = f % jb.MT, kk = f / jb.MT;
  int row = mt*16 + (lane & 15);
  int kb = kk*32 + (lane >> 4)*8;
  unsigned int pk[4];
  #pragma unroll
  for (int j=0;j<4;j++){
    unsigned short x0 = f2bf(jb.W[(size_t)row*jb.rs + (size_t)(kb+2*j)*jb.ks + jb.koff]);
    unsigned short x1 = f2bf(jb.W[(size_t)row*jb.rs + (size_t)(kb+2*j+1)*jb.ks + jb.koff]);
    pk[j] = (unsigned int)x0 | ((unsigned int)x1 << 16);
  }
  unsigned int* dst = (unsigned int*)(jb.dst + (size_t)gg*8);
  #pragma unroll
  for (int j=0;j<4;j++) dst[j] = pk[j];
}

// ---------------- x prep (bias computed inline) ----------------
__global__ __launch_bounds__(256) void k_xprep(const float* __restrict__ x,
    const float* __restrict__ degree_emb, const int* __restrict__ all_degree,
    unsigned short* __restrict__ xbf,
    unsigned short* __restrict__ xcl, unsigned short* __restrict__ xclr){
  __shared__ float xl[64][153];
  int tid = threadIdx.x;
  int t = blockIdx.x, n = blockIdx.y;
  for (int idx=tid; idx<64*160; idx+=256){
    int c = idx/160, v = idx - c*160;
    float xv = 0.f;
    if (v < VV){
      xv = x[((size_t)(n*CC+c)*TT + t)*VV + v];
      xl[c][v] = xv;
    }
    xbf[((size_t)(n*CC+c)*TT + t)*160 + v] = f2bf(xv);
  }
  __syncthreads();
  size_t pixb = (size_t)(n*TT + t)*VV;
  for (int idx=tid; idx<4800; idx+=256){
    int v = idx >> 5, c2 = (idx & 31)*2;
    float a0 = xl[c2][v], a1 = xl[c2+1][v];
    unsigned int raw = (unsigned int)f2bf(a0) | ((unsigned int)f2bf(a1) << 16);
    float freq = __expf(-(float)(c2 >> 1) * 0.2878231366f);
    float arg = (float)v * freq;
    int dgi = all_degree[v % 25];
    float b0 = a0 + sinf(arg) + degree_emb[dgi*CC + c2];
    float b1 = a1 + cosf(arg) + degree_emb[dgi*CC + c2 + 1];
    unsigned int bi = (unsigned int)f2bf(b0) | ((unsigned int)f2bf(b1) << 16);
    *(unsigned int*)(xclr + (pixb + v)*CC + c2) = raw;
    *(unsigned int*)(xcl  + (pixb + v)*CC + c2) = bi;
  }
}

// ---------------- qkv MFMA: M=512, K=64 ----------------
__global__ __launch_bounds__(256) void k_qkv_mfma(const unsigned short* __restrict__ xcl,
    const unsigned short* __restrict__ Wsw, const float* __restrict__ bq,
    unsigned short* __restrict__ qkv){
  int tid = threadIdx.x, wave = tid >> 6, lane = tid & 63;
  int l15 = lane & 15, lhi = lane >> 4;
  int pix0 = blockIdx.x*32;
  f32x4 acc[8][2];
  #pragma unroll
  for (int m=0;m<8;m++){ acc[m][0] = f32x4{0,0,0,0}; acc[m][1] = f32x4{0,0,0,0}; }
  #pragma unroll
  for (int kk=0;kk<2;kk++){
    bf16x8 bfr[2];
    #pragma unroll
    for (int q=0;q<2;q++)
      bfr[q] = *(const bf16x8*)(xcl + (size_t)(pix0 + q*16 + l15)*CC + kk*32 + lhi*8);
    #pragma unroll
    for (int m=0;m<8;m++){
      bf16x8 afr = *(const bf16x8*)(Wsw + ((size_t)(kk*32 + wave*8 + m)*64 + lane)*8);
      acc[m][0] = __builtin_amdgcn_mfma_f32_16x16x32_bf16(afr, bfr[0], acc[m][0], 0,0,0);
      acc[m][1] = __builtin_amdgcn_mfma_f32_16x16x32_bf16(afr, bfr[1], acc[m][1], 0,0,0);
    }
  }
  #pragma unroll
  for (int m=0;m<8;m++){
    int o0 = (wave*8 + m)*16 + lhi*4;
    float b0 = bq[o0], b1 = bq[o0+1], b2 = bq[o0+2], b3 = bq[o0+3];
    #pragma unroll
    for (int q=0;q<2;q++){
      int pix = pix0 + q*16 + l15;
      uint2 pk;
      pk.x = (unsigned int)f2bf(acc[m][q][0]+b0) | ((unsigned int)f2bf(acc[m][q][1]+b1) << 16);
      pk.y = (unsigned int)f2bf(acc[m][q][2]+b2) | ((unsigned int)f2bf(acc[m][q][3]+b3) << 16);
      *(uint2*)(qkv + (size_t)pix*QCH + o0) = pk;
    }
  }
}

// ---------------- att MFMA: grid (5 vt, 8 h, 16 n) ----------------
__global__ __launch_bounds__(256) void k_att_mfma(const unsigned short* __restrict__ qkv,
    const float* __restrict__ alphas, const float* __restrict__ att0s,
    const float* __restrict__ sp_emb, const int* __restrict__ sp_pos,
    unsigned short* __restrict__ attT){
  int tid = threadIdx.x, wave = tid >> 6, lane = tid & 63;
  int l15 = lane & 15, lhi = lane >> 4;
  int vt = blockIdx.x, h = blockIdx.y, n = blockIdx.z;
  int uhalf = wave & 1, vsel = wave >> 1;
  int v = (vt*2 + vsel)*16 + l15;
  f32x4 acc[5];
  #pragma unroll
  for (int ui=0;ui<5;ui++) acc[ui] = f32x4{0,0,0,0};
  for (int t=0;t<TT;t++){
    size_t rowb = (size_t)(n*TT + t)*VV;
    bf16x8 bfr = bf16x8{};
    if (v < VV) bfr = *(const bf16x8*)(qkv + (rowb + v)*QCH + 256 + h*DD + lhi*8);
    #pragma unroll
    for (int ui=0;ui<5;ui++){
      int u = (uhalf*5+ui)*16 + l15;
      bf16x8 afr = bf16x8{};
      if (u < VV) afr = *(const bf16x8*)(qkv + (rowb + u)*QCH + h*DD + lhi*8);
      acc[ui] = __builtin_amdgcn_mfma_f32_16x16x32_bf16(afr, bfr, acc[ui], 0,0,0);
    }
  }
  float al = alphas[h];
  #pragma unroll
  for (int ui=0;ui<5;ui++){
    int u0 = (uhalf*5+ui)*16 + lhi*4;
    unsigned short hv[4];
    #pragma unroll
    for (int r=0;r<4;r++){
      int u = u0 + r;
      unsigned short val = 0;
      if (u < VV && v < VV){
        float gv = tanhf(acc[ui][r]*(1.f/640.f))*al
                 + att0s[((size_t)h*VV + u)*VV + v]
                 + sp_emb[sp_pos[u*VV + v]*HH + h];
        val = f2bf(gv);
      }
      hv[r] = val;
    }
    uint2 pk;
    pk.x = (unsigned int)hv[0] | ((unsigned int)hv[1] << 16);
    pk.y = (unsigned int)hv[2] | ((unsigned int)hv[3] << 16);
    *(uint2*)(attT + ((size_t)((n*HH+h)*160) + v)*160 + u0) = pk;
  }
}

// ---------------- yapply MFMA: grid (8 h, 20 t, 16 n) ----------------
__global__ __launch_bounds__(256) void k_yapply_mfma(const unsigned short* __restrict__ attT,
    const unsigned short* __restrict__ xbf, unsigned short* __restrict__ ycl){
  int tid = threadIdx.x, wave = tid >> 6, lane = tid & 63;
  int l15 = lane & 15, lhi = lane >> 4;
  int h = blockIdx.x, t = blockIdx.y, n = blockIdx.z;
  int vtb = (wave & 1)*5, ctb = (wave >> 1)*2;
  f32x4 acc[5][2];
  #pragma unroll
  for (int vi=0;vi<5;vi++){ acc[vi][0] = f32x4{0,0,0,0}; acc[vi][1] = f32x4{0,0,0,0}; }
  #pragma unroll
  for (int kk=0;kk<5;kk++){
    bf16x8 bfr[2];
    #pragma unroll
    for (int ci=0;ci<2;ci++){
      int c = (ctb+ci)*16 + l15;
      bfr[ci] = *(const bf16x8*)(xbf + ((size_t)(n*CC+c)*TT + t)*160 + kk*32 + lhi*8);
    }
    #pragma unroll
    for (int vi=0;vi<5;vi++){
      int v = (vtb+vi)*16 + l15;
      bf16x8 afr = *(const bf16x8*)(attT + ((size_t)((n*HH+h)*160) + v)*160 + kk*32 + lhi*8);
      #pragma unroll
      for (int ci=0;ci<2;ci++)
        acc[vi][ci] = __builtin_amdgcn_mfma_f32_16x16x32_bf16(afr, bfr[ci], acc[vi][ci], 0,0,0);
    }
  }
  size_t pixb = (size_t)(n*TT + t)*VV;
  #pragma unroll
  for (int vi=0;vi<5;vi++){
    int v0 = (vtb+vi)*16 + lhi*4;
    #pragma unroll
    for (int ci=0;ci<2;ci++){
      int c = (ctb+ci)*16 + l15;
      #pragma unroll
      for (int r=0;r<4;r++){
        int v = v0 + r;
        if (v < VV)
          ycl[(pixb + v)*QCH + h*CC + c] = f2bf(acc[vi][ci][r]);
      }
    }
  }
}

// ---------------- conv_out MFMA: grid (5 vt, 5 tq, 16 n); wave = 4m x 4t x 1 v-tile ----------------
__global__ __launch_bounds__(256) void k_conv_out_mfma(const unsigned short* __restrict__ ycl,
    const unsigned short* __restrict__ Wsw, float* __restrict__ out){
  int tid = threadIdx.x, wave = tid >> 6, lane = tid & 63;
  int l15 = lane & 15, lhi = lane >> 4;
  int vt = blockIdx.x, tq = blockIdx.y, n = blockIdx.z;
  int mtb = (wave & 1)*4;
  int ntile = wave >> 1;
  int t0 = tq*4;
  int v = vt*32 + ntile*16 + l15;
  f32x4 acc[4][4];
  #pragma unroll
  for (int m=0;m<4;m++)
    #pragma unroll
    for (int tj=0;tj<4;tj++) acc[m][tj] = f32x4{0,0,0,0};
  for (int kk=0; kk<16; kk++){
    #pragma unroll
    for (int kv=0; kv<5; kv++){
      bf16x8 afr[4];
      #pragma unroll
      for (int m=0;m<4;m++)
        afr[m] = *(const bf16x8*)(Wsw + (size_t)kv*65536 + ((size_t)(kk*8 + mtb + m)*64 + lane)*8);
      int vv = v + kv - 2;
      bool vok = (vv >= 0) && (vv < VV);
      #pragma unroll
      for (int tj=0;tj<4;tj++){
        bf16x8 bfr = bf16x8{};
        if (vok)
          bfr = *(const bf16x8*)(ycl + ((size_t)(n*TT + t0 + tj)*VV + vv)*QCH + kk*32 + lhi*8);
        #pragma unroll
        for (int m=0;m<4;m++)
          acc[m][tj] = __builtin_amdgcn_mfma_f32_16x16x32_bf16(afr[m], bfr, acc[m][tj], 0,0,0);
      }
    }
  }
  if (v < VV){
    #pragma unroll
    for (int tj=0;tj<4;tj++){
      size_t pb = ((size_t)(n*TT + t0 + tj)*VV + v)*OO;
      #pragma unroll
      for (int m=0;m<4;m++){
        int o0 = (mtb+m)*16 + lhi*4;
        *(float4*)(out + pb + o0) = make_float4(acc[m][tj][0], acc[m][tj][1], acc[m][tj][2], acc[m][tj][3]);
      }
    }
  }
}

// ---------------- 1x1 conv MFMA: grid 750; wave = 4m x 2 pixel-tiles ----------------
__global__ __launch_bounds__(256) void k_conv1x1_mfma(const unsigned short* __restrict__ in,
    const unsigned short* __restrict__ Wsw, float* __restrict__ out, int KT){
  int tid = threadIdx.x, wave = tid >> 6, lane = tid & 63;
  int l15 = lane & 15, lhi = lane >> 4;
  int mtb = (wave & 1)*4;
  int pg = wave >> 1;
  int pixb = blockIdx.x*64 + pg*32;
  int KD = KT*32;
  f32x4 acc[4][2];
  #pragma unroll
  for (int m=0;m<4;m++){ acc[m][0] = f32x4{0,0,0,0}; acc[m][1] = f32x4{0,0,0,0}; }
  for (int kk=0; kk<KT; kk++){
    bf16x8 bfr[2];
    #pragma unroll
    for (int pj=0;pj<2;pj++)
      bfr[pj] = *(const bf16x8*)(in + (size_t)(pixb + pj*16 + l15)*KD + kk*32 + lhi*8);
    #pragma unroll
    for (int m=0;m<4;m++){
      bf16x8 afr = *(const bf16x8*)(Wsw + ((size_t)(kk*8 + mtb + m)*64 + lane)*8);
      acc[m][0] = __builtin_amdgcn_mfma_f32_16x16x32_bf16(afr, bfr[0], acc[m][0], 0,0,0);
      acc[m][1] = __builtin_amdgcn_mfma_f32_16x16x32_bf16(afr, bfr[1], acc[m][1], 0,0,0);
    }
  }
  #pragma unroll
  for (int m=0;m<4;m++){
    int o0 = (mtb+m)*16 + lhi*4;
    #pragma unroll
    for (int pj=0;pj<2;pj++){
      int pix = pixb + pj*16 + l15;
      *(float4*)(out + (size_t)pix*OO + o0) = make_float4(acc[m][pj][0], acc[m][pj][1], acc[m][pj][2], acc[m][pj][3]);
    }
  }
}

// ---------------- conv_t MFMA: 3x1 along T; grid (5 vt, 5 tq, 16 n); wave = 4m x 4t ----------------
__global__ __launch_bounds__(256) void k_conv_t_mfma(const unsigned short* __restrict__ in,
    const unsigned short* __restrict__ Wsw, float* __restrict__ out){
  int tid = threadIdx.x, wave = tid >> 6, lane = tid & 63;
  int l15 = lane & 15, lhi = lane >> 4;
  int vt = blockIdx.x, tq = blockIdx.y, n = blockIdx.z;
  int mtb = (wave & 1)*4;
  int ntile = wave >> 1;
  int t0 = tq*4;
  int v = vt*32 + ntile*16 + l15;
  bool vok = v < VV;
  f32x4 acc[4][4];
  #pragma unroll
  for (int m=0;m<4;m++)
    #pragma unroll
    for (int tj=0;tj<4;tj++) acc[m][tj] = f32x4{0,0,0,0};
  #pragma unroll
  for (int kk=0; kk<4; kk++){
    bf16x8 bfr[6];
    #pragma unroll
    for (int r=0;r<6;r++){
      int tt = t0 + r - 1;
      bfr[r] = bf16x8{};
      if (vok && tt >= 0 && tt < TT)
        bfr[r] = *(const bf16x8*)(in + ((size_t)(n*TT + tt)*VV + v)*OO + kk*32 + lhi*8);
    }
    #pragma unroll
    for (int kt=0; kt<3; kt++){
      bf16x8 afr[4];
      #pragma unroll
      for (int m=0;m<4;m++)
        afr[m] = *(const bf16x8*)(Wsw + (size_t)kt*16384 + ((size_t)(kk*8 + mtb + m)*64 + lane)*8);
      #pragma unroll
      for (int tj=0;tj<4;tj++)
        #pragma unroll
        for (int m=0;m<4;m++)
          acc[m][tj] = __builtin_amdgcn_mfma_f32_16x16x32_bf16(afr[m], bfr[tj+kt], acc[m][tj], 0,0,0);
    }
  }
  if (vok){
    #pragma unroll
    for (int tj=0;tj<4;tj++){
      size_t pb = ((size_t)(n*TT + t0 + tj)*VV + v)*OO;
      #pragma unroll
      for (int m=0;m<4;m++){
        int o0 = (mtb+m)*16 + lhi*4;
        *(float4*)(out + pb + o0) = make_float4(acc[m][tj][0], acc[m][tj][1], acc[m][tj][2], acc[m][tj][3]);
      }
    }
  }
}

// ---------------- stats stage 1 ----------------
__global__ __launch_bounds__(256) void k_stats1(const float* __restrict__ in, float* __restrict__ psum){
  int tid = threadIdx.x, blk = blockIdx.x;
  int ch = tid & 127, half = tid >> 7;
  float s = 0.f, s2 = 0.f;
  for (int i=0;i<192;i++){
    int p = blk*384 + i*2 + half;
    float v = in[(size_t)p*OO + ch];
    s += v; s2 += v*v;
  }
  int idx = (blk*2 + half)*OO + ch;
  psum[idx] = s;
  psum[32000 + idx] = s2;
}

// ---------------- stats stage 2 ----------------
__global__ __launch_bounds__(64) void k_stats2(const float* __restrict__ psum, float* __restrict__ st){
  int ch = blockIdx.x, tid = threadIdx.x;
  float s = 0.f, s2 = 0.f;
  for (int i=tid;i<250;i+=64){
    s  += psum[i*OO + ch];
    s2 += psum[32000 + i*OO + ch];
  }
  #pragma unroll
  for (int off=32; off; off>>=1){ s += __shfl_down(s, off); s2 += __shfl_down(s2, off); }
  if (tid == 0){
    float m = s * (1.f/48000.f);
    float var = s2 * (1.f/48000.f) - m*m;
    st[ch*2] = m;
    st[ch*2+1] = rsqrtf(var + 1e-5f);
  }
}

// ---------------- BN in-place (residual) ----------------
__global__ __launch_bounds__(256) void k_bn_rs(float* __restrict__ buf,
    const float* __restrict__ st, const float* __restrict__ g, const float* __restrict__ be){
  int i = (blockIdx.x*256 + threadIdx.x)*4;
  if (i >= NEL) return;
  int ch = i & 127;
  float4 v = *(float4*)(buf + i);
  v.x = (v.x - st[ch*2+0]) * st[ch*2+1] * g[ch+0] + be[ch+0];
  v.y = (v.y - st[ch*2+2]) * st[ch*2+3] * g[ch+1] + be[ch+1];
  v.z = (v.z - st[ch*2+4]) * st[ch*2+5] * g[ch+2] + be[ch+2];
  v.w = (v.w - st[ch*2+6]) * st[ch*2+7] * g[ch+3] + be[ch+3];
  *(float4*)(buf + i) = v;
}

// ---------------- xs = bf16(lrelu(bn(c) + res)) ----------------
__global__ __launch_bounds__(256) void k_bn_xs(const float* __restrict__ c,
    const float* __restrict__ st, const float* __restrict__ g, const float* __restrict__ be,
    const float* __restrict__ res, unsigned short* __restrict__ xs){
  int i = (blockIdx.x*256 + threadIdx.x)*4;
  if (i >= NEL) return;
  int ch = i & 127;
  float4 v = *(const float4*)(c + i);
  float4 r = *(const float4*)(res + i);
  float o0 = lrelu((v.x - st[ch*2+0]) * st[ch*2+1] * g[ch+0] + be[ch+0] + r.x);
  float o1 = lrelu((v.y - st[ch*2+2]) * st[ch*2+3] * g[ch+1] + be[ch+1] + r.y);
  float o2 = lrelu((v.z - st[ch*2+4]) * st[ch*2+5] * g[ch+2] + be[ch+2] + r.z);
  float o3 = lrelu((v.w - st[ch*2+6]) * st[ch*2+7] * g[ch+3] + be[ch+3] + r.w);
  uint2 pk;
  pk.x = (unsigned int)f2bf(o0) | ((unsigned int)f2bf(o1) << 16);
  pk.y = (unsigned int)f2bf(o2) | ((unsigned int)f2bf(o3) << 16);
  *(uint2*)(xs + i) = pk;
}

// ---------------- final ----------------
__global__ __launch_bounds__(256) void k_final_cl(const float* __restrict__ c3,
    const float* __restrict__ st3, const float* __restrict__ g3, const float* __restrict__ be3,
    const float* __restrict__ c4, const float* __restrict__ st4, const float* __restrict__ g4,
    const float* __restrict__ be4, float* __restrict__ out){
  __shared__ float tile[64][153];
  int tid = threadIdx.x;
  int t = blockIdx.x, n = blockIdx.y;
  size_t pixb = (size_t)(n*TT + t)*VV;
  for (int ch0=0; ch0<OO; ch0+=64){
    __syncthreads();
    for (int idx=tid; idx<VV*64; idx+=256){
      int v = idx >> 6, cc = idx & 63;
      int ch = ch0 + cc;
      float a = (c3[(pixb+v)*OO + ch] - st3[ch*2]) * st3[ch*2+1] * g3[ch] + be3[ch];
      float b = (c4[(pixb+v)*OO + ch] - st4[ch*2]) * st4[ch*2+1] * g4[ch] + be4[ch];
      tile[cc][v] = lrelu(a + b);
    }
    __syncthreads();
    for (int idx=tid; idx<64*VV; idx+=256){
      int cc = idx / VV, v = idx - cc*VV;
      out[((size_t)(n*OO + ch0 + cc)*TT + t)*VV + v] = tile[cc][v];
    }
  }
}

extern "C" void kernel_launch(void* const* d_in, const int* in_sizes, int n_in,
                              void* d_out, int out_size, void* d_ws, size_t ws_size,
                              hipStream_t stream) {
  const float* x        = (const float*)d_in[0];
  const float* W_qkv    = (const float*)d_in[1];
  const float* b_qkv    = (const float*)d_in[2];
  const float* alphas   = (const float*)d_in[3];
  const float* att0s    = (const float*)d_in[4];
  const float* degree_emb = (const float*)d_in[5];
  const float* spatial_emb = (const float*)d_in[6];
  const float* W_out    = (const float*)d_in[7];
  const float* g_out    = (const float*)d_in[9];
  const float* be_out   = (const float*)d_in[10];
  const float* W_ff     = (const float*)d_in[11];
  const float* g_ff     = (const float*)d_in[13];
  const float* be_ff    = (const float*)d_in[14];
  const float* W_t      = (const float*)d_in[15];
  const float* g_t      = (const float*)d_in[17];
  const float* be_t     = (const float*)d_in[18];
  const float* W_rs     = (const float*)d_in[19];
  const float* g_rs     = (const float*)d_in[21];
  const float* be_rs    = (const float*)d_in[22];
  const float* W_rt     = (const float*)d_in[23];
  const float* g_rt     = (const float*)d_in[25];
  const float* be_rt    = (const float*)d_in[26];
  const int* all_degree = (const int*)d_in[27];
  const int* spatial_pos= (const int*)d_in[28];

  char* ws = (char*)d_ws;
  unsigned short* qkvcl = (unsigned short*)(ws + 0);
  unsigned short* ycl   = qkvcl;
  float* c1 = (float*)(ws + 49200000);
  float* c2 = c1, *c3 = c1;
  unsigned short* attT = (unsigned short*)(ws + 73800000);
  float* rsb = (float*)(ws + 73800000);
  float* c4  = (float*)(ws + 73800000);
  unsigned short* xclr = (unsigned short*)(ws + 98400000);
  unsigned short* xs1  = (unsigned short*)(ws + 98400000);
  unsigned short* xbf  = (unsigned short*)(ws + 110700000);
  unsigned short* xs2  = (unsigned short*)(ws + 110700000);
  unsigned short* xcl  = (unsigned short*)(ws + 123000000);
  unsigned short* Wq_sw  = (unsigned short*)(ws + 129200000);
  unsigned short* Wout_sw= (unsigned short*)(ws + 129200000 + 65536);
  unsigned short* Wff_sw = (unsigned short*)(ws + 129200000 + 720896);
  unsigned short* Wrt_sw = (unsigned short*)(ws + 129200000 + 753664);
  unsigned short* Wt_sw  = (unsigned short*)(ws + 129200000 + 786432);
  unsigned short* Wrs_sw = (unsigned short*)(ws + 129200000 + 884736);
  float* stats = (float*)(ws + 130250000);
  float* psum  = (float*)(ws + 130260000);
  float* out = (float*)d_out;

  WprepArgs wa;
  int base = 0, sz;
  // job 0: W_qkv
  sz = 32*2*64; wa.j[0] = {W_qkv, Wq_sw, 32, 2, 64, 1, 0, base}; base += sz;
  // jobs 1-5: W_out kv=0..4
  for (int kv=0; kv<5; kv++){
    sz = 8*16*64; wa.j[1+kv] = {W_out, Wout_sw + kv*65536, 8, 16, 2560, 5, kv, base}; base += sz;
  }
  sz = 8*4*64; wa.j[6] = {W_ff, Wff_sw, 8, 4, 128, 1, 0, base}; base += sz;
  sz = 8*4*64; wa.j[7] = {W_rt, Wrt_sw, 8, 4, 128, 1, 0, base}; base += sz;
  for (int kt=0; kt<3; kt++){
    sz = 8*4*64; wa.j[8+kt] = {W_t, Wt_sw + kt*16384, 8, 4, 384, 3, kt, base}; base += sz;
  }
  sz = 8*2*64; wa.j[11] = {W_rs, Wrs_sw, 8, 2, 64, 1, 0, base}; base += sz;
  int total = base;

  k_wprep_all<<<(total+255)/256, 256, 0, stream>>>(wa, total);
  k_xprep<<<dim3(20,16), 256, 0, stream>>>(x, degree_emb, all_degree, xbf, xcl, xclr);
  k_qkv_mfma<<<1500, 256, 0, stream>>>(xcl, Wq_sw, b_qkv, qkvcl);
  k_att_mfma<<<dim3(5,8,16), 256, 0, stream>>>(qkvcl, alphas, att0s, spatial_emb, spatial_pos, attT);
  k_yapply_mfma<<<dim3(8,20,16), 256, 0, stream>>>(attT, xbf, ycl);

  k_conv1x1_mfma<<<750, 256, 0, stream>>>(xclr, Wrs_sw, rsb, 2);
  k_stats1<<<125, 256, 0, stream>>>(rsb, psum);
  k_stats2<<<128, 64, 0, stream>>>(psum, stats + 0);
  k_bn_rs<<<6000, 256, 0, stream>>>(rsb, stats + 0, g_rs, be_rs);

  k_conv_out_mfma<<<dim3(5,5,16), 256, 0, stream>>>(ycl, Wout_sw, c1);
  k_stats1<<<125, 256, 0, stream>>>(c1, psum);
  k_stats2<<<128, 64, 0, stream>>>(psum, stats + 256);
  k_bn_xs<<<6000, 256, 0, stream>>>(c1, stats + 256, g_out, be_out, rsb, xs1);

  k_conv1x1_mfma<<<750, 256, 0, stream>>>(xs1, Wff_sw, c2, 4);
  k_stats1<<<125, 256, 0, stream>>>(c2, psum);
  k_stats2<<<128, 64, 0, stream>>>(psum, stats + 512);
  k_bn_xs<<<6000, 256, 0, stream>>>(c2, stats + 512, g_ff, be_ff, rsb, xs2);

  k_conv_t_mfma<<<dim3(5,5,16), 256, 0, stream>>>(xs2, Wt_sw, c3);
  k_conv1x1_mfma<<<750, 256, 0, stream>>>(xs2, Wrt_sw, c4, 4);
  k_stats1<<<125, 256, 0, stream>>>(c3, psum);
  k_stats2<<<128, 64, 0, stream>>>(psum, stats + 768);
  k_stats1<<<125, 256, 0, stream>>>(c4, psum);
  k_stats2<<<128, 64, 0, stream>>>(psum, stats + 1024);
  k_final_cl<<<dim3(20,16), 256, 0, stream>>>(c3, stats + 768, g_t, be_t,
                                              c4, stats + 1024, g_rt, be_rt, out);
}